// Round 7
// baseline (1540.813 us; speedup 1.0000x reference)
//
#include <hip/hip_runtime.h>
#include <cstdint>

#define HW 131072        // H*W
#define S_ELEMS 16777216 // B*C*H*W

// ---------------- BN stats (both sides): emit scale/shift ----------------
__global__ __launch_bounds__(256) void bn_stats_k(const float* __restrict__ xL,
                                                  const float* __restrict__ xR,
                                                  const float* __restrict__ gamma,
                                                  const float* __restrict__ beta,
                                                  float* __restrict__ stats) {
  int side = blockIdx.x >> 6;
  int c = blockIdx.x & 63;
  const float* x = side ? xR : xL;
  float s1 = 0.f, s2 = 0.f;
  for (int bb = 0; bb < 2; ++bb) {
    const float4* p = (const float4*)(x + ((size_t)(bb * 64 + c)) * HW);
    for (int i = threadIdx.x; i < HW / 4; i += 256) {
      float4 v = p[i];
      s1 += v.x + v.y + v.z + v.w;
      s2 += v.x * v.x + v.y * v.y + v.z * v.z + v.w * v.w;
    }
  }
  for (int m = 32; m; m >>= 1) {
    s1 += __shfl_xor(s1, m, 64);
    s2 += __shfl_xor(s2, m, 64);
  }
  __shared__ float r1[4], r2[4];
  int wv = threadIdx.x >> 6;
  if ((threadIdx.x & 63) == 0) { r1[wv] = s1; r2[wv] = s2; }
  __syncthreads();
  if (threadIdx.x == 0) {
    float t1 = r1[0] + r1[1] + r1[2] + r1[3];
    float t2 = r2[0] + r2[1] + r2[2] + r2[3];
    float mu = t1 / 262144.f;
    float var = t2 / 262144.f - mu * mu;
    float rs = rsqrtf(var + 1e-5f);
    float sc = rs * gamma[c];
    stats[side * 128 + c] = sc;
    stats[side * 128 + 64 + c] = beta[c] - mu * sc;
  }
}

// ---------------- tiled grouped 3x3 conv ----------------
// block: (b, g, 8-row x 64-col tile); computes all 16 output channels of group.
// BNIN: apply y=x*sc+sh while staging input. RES: add bn(xres) in epilogue.
template <bool BNIN, bool LEAKY, bool RES>
__global__ __launch_bounds__(256) void conv3x3_t(const float* __restrict__ in,
                                                 const float* __restrict__ wgt,
                                                 const float* __restrict__ bias,
                                                 const float* __restrict__ ss,
                                                 const float* __restrict__ xres,
                                                 float* __restrict__ out) {
  __shared__ float sIn[16 * 10 * 68];
  __shared__ float sW[16 * 16 * 3 * 4];  // [o][ci][kh] -> float4 {w0,w1,w2,pad}
  __shared__ float sSc[16], sSh[16];
  int bid = blockIdx.x;
  int tw = bid & 7, th = (bid >> 3) & 31, g = (bid >> 8) & 3, b = bid >> 10;
  int tid = threadIdx.x;
  for (int e = tid; e < 2304; e += 256) {
    int o = e / 144, rem = e - o * 144, ci = rem / 9, k = rem - ci * 9;
    sW[((o * 16 + ci) * 3 + k / 3) * 4 + k % 3] = wgt[(g * 16 + o) * 144 + rem];
  }
  if ((BNIN || RES) && tid < 16) { sSc[tid] = ss[g * 16 + tid]; sSh[tid] = ss[64 + g * 16 + tid]; }
  int h0 = th * 8 - 1, w0 = tw * 64 - 1;
  const float* inb = in + ((size_t)(b * 64 + g * 16)) * HW;
  for (int e = tid; e < 10560; e += 256) {
    int ci = e / 660, rem = e - ci * 660, r = rem / 66, c = rem - r * 66;
    int h = h0 + r, w = w0 + c;
    float v = 0.f;
    if ((unsigned)h < 256u && (unsigned)w < 512u) {
      v = inb[(size_t)ci * HW + h * 512 + w];
      if (BNIN) v = v * sSc[ci] + sSh[ci];
    }
    sIn[ci * 680 + r * 68 + c] = v;
  }
  __syncthreads();
  int oh = tid >> 7;  // 0..1 : output-channel half
  int pxi = tid & 127;
  int row = pxi >> 4, col = (pxi & 15) * 4;
  float acc[8][4];
#pragma unroll
  for (int o = 0; o < 8; ++o) {
    float bz = bias[g * 16 + oh * 8 + o];
#pragma unroll
    for (int p = 0; p < 4; ++p) acc[o][p] = bz;
  }
  for (int ci = 0; ci < 16; ++ci) {
    float v[3][6];
    const float* base = sIn + ci * 680 + row * 68 + col;
#pragma unroll
    for (int kh = 0; kh < 3; ++kh) {
      float4 a4 = *(const float4*)(base + kh * 68);
      float2 a2 = *(const float2*)(base + kh * 68 + 4);
      v[kh][0] = a4.x; v[kh][1] = a4.y; v[kh][2] = a4.z; v[kh][3] = a4.w;
      v[kh][4] = a2.x; v[kh][5] = a2.y;
    }
    const float4* wb = (const float4*)sW + ((oh * 8) * 16 + ci) * 3;
#pragma unroll
    for (int o = 0; o < 8; ++o) {
      const float4* wo = wb + o * 48;
#pragma unroll
      for (int kh = 0; kh < 3; ++kh) {
        float4 wv = wo[kh];
#pragma unroll
        for (int p = 0; p < 4; ++p)
          acc[o][p] += wv.x * v[kh][p] + wv.y * v[kh][p + 1] + wv.z * v[kh][p + 2];
      }
    }
  }
  int h = th * 8 + row, wcol = tw * 64 + col;
#pragma unroll
  for (int o = 0; o < 8; ++o) {
    int cg = g * 16 + oh * 8 + o;
    size_t off = ((size_t)(b * 64 + cg)) * HW + h * 512 + wcol;
    float4 r4;
    float* rp = (float*)&r4;
    if (RES) {
      float4 x4 = *(const float4*)(xres + off);
      float sc = sSc[oh * 8 + o], sh = sSh[oh * 8 + o];
      float xr0 = x4.x * sc + sh, xr1 = x4.y * sc + sh, xr2 = x4.z * sc + sh, xr3 = x4.w * sc + sh;
      float a0 = acc[o][0], a1 = acc[o][1], a2 = acc[o][2], a3 = acc[o][3];
      if (LEAKY) { a0 = a0 > 0 ? a0 : 0.1f * a0; a1 = a1 > 0 ? a1 : 0.1f * a1; a2 = a2 > 0 ? a2 : 0.1f * a2; a3 = a3 > 0 ? a3 : 0.1f * a3; }
      rp[0] = a0 + xr0; rp[1] = a1 + xr1; rp[2] = a2 + xr2; rp[3] = a3 + xr3;
    } else {
#pragma unroll
      for (int p = 0; p < 4; ++p) {
        float a = acc[o][p];
        if (LEAKY) a = a > 0.f ? a : 0.1f * a;
        rp[p] = a;
      }
    }
    *(float4*)(out + off) = r4;
  }
}

// ---------------- 1x1 qkv conv: thread = pixel, all 192 outputs ----------------
__global__ __launch_bounds__(256) void qkv_k(const float* __restrict__ r,
                                             const float* __restrict__ wgt,
                                             const float* __restrict__ bias,
                                             float* __restrict__ qout,
                                             float* __restrict__ kvout) {
  __shared__ float sW[3072];
  __shared__ float sB[192];
  int tid = threadIdx.x;
  for (int e = tid; e < 3072; e += 256) sW[e] = wgt[e];
  if (tid < 192) sB[tid] = bias[tid];
  __syncthreads();
  int idx = blockIdx.x * 256 + tid;  // over B*HW
  int p = idx & (HW - 1);
  int b = idx >> 17;
  const float* rb = r + (size_t)b * 64 * HW + p;
  float* qb = qout + (size_t)b * 64 * HW + p;
  float* kvb = kvout + (size_t)b * 128 * HW + p;
  for (int g = 0; g < 4; ++g) {
    float in[16];
#pragma unroll
    for (int ci = 0; ci < 16; ++ci) in[ci] = rb[(size_t)(g * 16 + ci) * HW];
    for (int oo = 0; oo < 48; ++oo) {
      int o = g * 48 + oo;
      const float4* w4 = (const float4*)(sW + o * 16);
      float acc = sB[o];
#pragma unroll
      for (int q = 0; q < 4; ++q) {
        float4 wv = w4[q];
        acc += wv.x * in[q * 4] + wv.y * in[q * 4 + 1] + wv.z * in[q * 4 + 2] + wv.w * in[q * 4 + 3];
      }
      if (o < 64) qb[(size_t)o * HW] = acc;
      else kvb[(size_t)(o - 64) * HW] = acc;
    }
  }
}

// ---------------- fused per-window attention (LDS-reuse, pad-65) ----------------
__global__ __launch_bounds__(256) void attn_fused_k(const float* __restrict__ qL,
                                                    const float* __restrict__ qR,
                                                    const float* __restrict__ kvL,
                                                    const float* __restrict__ kvR,
                                                    const float* __restrict__ dL,
                                                    const float* __restrict__ dR,
                                                    const float* __restrict__ xL,
                                                    const float* __restrict__ xR,
                                                    float* __restrict__ outL,
                                                    float* __restrict__ outR) {
  const int n = blockIdx.x;
  const int b = n >> 11;
  const int hb = (n >> 6) & 31;
  const int wb = n & 63;
  const int tid = threadIdx.x;

  // A: Ql[j][c] -> Mr2l[j][k];  B: Qr[j][c] -> Ml2r[j][k]
  // C: Kr[c2][k] -> Vr_sel[k][c];  D: Kl[c2][k] -> Vl_sel[k][c]
  __shared__ float A[4160], B[4160], C[4160], D[4160];
  __shared__ float mA[64], mB[64];  // means, then m_left / m_right maps

  const float* Qlb = qL + (size_t)b * 64 * HW;
  const float* Qrb = qR + (size_t)b * 64 * HW;
  const float* Klb = kvL + (size_t)b * 128 * HW;
  const float* Vlb = Klb + (size_t)64 * HW;
  const float* Krb = kvR + (size_t)b * 128 * HW;
  const float* Vrb = Krb + (size_t)64 * HW;
  const float* dLb = dL + (size_t)b * HW;
  const float* dRb = dR + (size_t)b * HW;

  // Phase 1: Q load + K gather
  for (int idx = tid; idx < 4096; idx += 256) {
    int c = idx >> 6, j = idx & 63;
    int hp = hb * 8 + (j >> 3), wp = wb * 8 + (j & 7);
    size_t off = (size_t)c * HW + hp * 512 + wp;
    A[j * 65 + c] = Qlb[off];
    B[j * 65 + c] = Qrb[off];
  }
  for (int idx = tid; idx < 4096; idx += 256) {
    int c2 = idx >> 6, k = idx & 63;
    int s = hb * 4096 + (k >> 3) * 512 + wb * 8 + (k & 7);
    int hh = 4 * c2 + (s >> 15);
    int rem = s & 32767;
    int ww = rem >> 6, cc = rem & 63;
    int dpos = hh * 512 + ww;
    int iwr = ww - (int)dLb[dpos]; iwr = min(max(iwr, 0), 511);
    int iwl = ww + (int)dRb[dpos]; iwl = min(max(iwl, 0), 511);
    C[c2 * 65 + k] = Krb[(size_t)cc * HW + hh * 512 + iwr];
    D[c2 * 65 + k] = Klb[(size_t)cc * HW + hh * 512 + iwl];
  }
  __syncthreads();
  // K means per hi over (c2, wi)
  {
    int grp = tid >> 5;  // hi
    int lane = tid & 31;
    float s1 = 0.f, s2 = 0.f;
    for (int e = lane; e < 512; e += 32) {
      int c2 = e >> 3, wi = e & 7;
      s1 += C[c2 * 65 + grp * 8 + wi];
      s2 += D[c2 * 65 + grp * 8 + wi];
    }
    for (int m = 16; m; m >>= 1) {
      s1 += __shfl_xor(s1, m, 32);
      s2 += __shfl_xor(s2, m, 32);
    }
    if (lane == 0) { mA[grp] = s1 * (1.f / 512.f); mB[grp] = s2 * (1.f / 512.f); }
  }
  __syncthreads();
  for (int idx = tid; idx < 4096; idx += 256) {
    int c2 = idx >> 6, k = idx & 63;
    int hi = k >> 3;
    C[c2 * 65 + k] -= mA[hi];
    D[c2 * 65 + k] -= mB[hi];
  }
  __syncthreads();
  // Phase 2: scores in registers. rows j0+16a, cols k0+d
  const int j0 = tid & 15;
  const int k0 = (tid >> 4) * 4;
  float aR[4][4] = {{0.f}}, aL[4][4] = {{0.f}};
  for (int c = 0; c < 64; ++c) {
    float ql[4], qr[4], kr[4], kl[4];
#pragma unroll
    for (int a = 0; a < 4; ++a) { ql[a] = A[(j0 + 16 * a) * 65 + c]; qr[a] = B[(j0 + 16 * a) * 65 + c]; }
#pragma unroll
    for (int d = 0; d < 4; ++d) { kr[d] = C[c * 65 + k0 + d]; kl[d] = D[c * 65 + k0 + d]; }
#pragma unroll
    for (int a = 0; a < 4; ++a)
#pragma unroll
      for (int d = 0; d < 4; ++d) {
        aR[a][d] += ql[a] * kr[d];
        aL[a][d] += qr[a] * kl[d];
      }
  }
  __syncthreads();
  // Phase 3: write scores into A/B; gather V into C/D
#pragma unroll
  for (int a = 0; a < 4; ++a)
#pragma unroll
    for (int d = 0; d < 4; ++d) {
      A[(j0 + 16 * a) * 65 + k0 + d] = aR[a][d];
      B[(j0 + 16 * a) * 65 + k0 + d] = aL[a][d];
    }
  for (int idx = tid; idx < 4096; idx += 256) {
    int k2 = idx >> 6, c2 = idx & 63;
    int s = hb * 4096 + (k2 >> 3) * 512 + wb * 8 + (k2 & 7);
    int hh = 4 * c2 + (s >> 15);
    int rem = s & 32767;
    int ww = rem >> 6, cc = rem & 63;
    int dpos = hh * 512 + ww;
    int iwr = ww - (int)dLb[dpos]; iwr = min(max(iwr, 0), 511);
    int iwl = ww + (int)dRb[dpos]; iwl = min(max(iwl, 0), 511);
    C[k2 * 65 + c2] = Vrb[(size_t)cc * HW + hh * 512 + iwr];
    D[k2 * 65 + c2] = Vlb[(size_t)cc * HW + hh * 512 + iwl];
  }
  __syncthreads();
  // Phase 4: softmax, one row per thread (128 rows)
  if (tid < 128) {
    float* row = (tid < 64 ? A : B) + (tid & 63) * 65;
    float mx = row[0];
    for (int k = 1; k < 64; ++k) mx = fmaxf(mx, row[k]);
    float s = 0.f;
    for (int k = 0; k < 64; ++k) {
      float e = __expf(row[k] - mx);
      row[k] = e;
      s += e;
    }
    float rs = 1.f / s;
    for (int k = 0; k < 64; ++k) row[k] *= rs;
  }
  __syncthreads();
  // Phase 5: m maps (128 threads)
  if (tid < 128) {
    int j = tid & 63;
    float acc = 0.f;
    if (tid < 64) {
      for (int k = 0; k < 64; ++k) {
        float rx = 0.f;
#pragma unroll
        for (int i = -2; i <= 2; ++i) {
          int jj = j + i;
          if (jj >= 0 && jj < 64) rx += A[jj * 65 + k];
        }
        acc += rx * B[k * 65 + j];
      }
      mA[j] = tanhf(5.f * acc);  // m_left
    } else {
      for (int k = 0; k < 64; ++k) {
        float rx = 0.f;
#pragma unroll
        for (int i = -2; i <= 2; ++i) {
          int jj = j + i;
          if (jj >= 0 && jj < 64) rx += B[jj * 65 + k];
        }
        acc += rx * A[k * 65 + j];
      }
      mB[j] = tanhf(5.f * acc);  // m_right
    }
  }
  __syncthreads();
  // Phase 6: PV + blend + store. rows j0+16a, channels c0+d
  const int c0 = k0;
  float oL[4][4] = {{0.f}}, oR[4][4] = {{0.f}};
  for (int k = 0; k < 64; ++k) {
    float mr[4], ml[4], vr[4], vl[4];
#pragma unroll
    for (int a = 0; a < 4; ++a) { mr[a] = A[(j0 + 16 * a) * 65 + k]; ml[a] = B[(j0 + 16 * a) * 65 + k]; }
#pragma unroll
    for (int d = 0; d < 4; ++d) { vr[d] = C[k * 65 + c0 + d]; vl[d] = D[k * 65 + c0 + d]; }
#pragma unroll
    for (int a = 0; a < 4; ++a)
#pragma unroll
      for (int d = 0; d < 4; ++d) {
        oL[a][d] += mr[a] * vr[d];
        oR[a][d] += ml[a] * vl[d];
      }
  }
#pragma unroll
  for (int a = 0; a < 4; ++a) {
    int j = j0 + 16 * a;
    int hp = hb * 8 + (j >> 3), wp = wb * 8 + (j & 7);
    float mlj = mA[j], mrj = mB[j];
#pragma unroll
    for (int d = 0; d < 4; ++d) {
      int c = c0 + d;
      size_t off = ((size_t)(b * 64 + c)) * HW + hp * 512 + wp;
      outL[off] = xL[off] * (1.f - mlj) + oL[a][d] * mlj;
      outR[off] = xR[off] * (1.f - mrj) + oR[a][d] * mrj;
    }
  }
}

extern "C" void kernel_launch(void* const* d_in, const int* in_sizes, int n_in,
                              void* d_out, int out_size, void* d_ws, size_t ws_size,
                              hipStream_t stream) {
  const float* x_left = (const float*)d_in[0];
  const float* x_right = (const float*)d_in[1];
  const float* d_left = (const float*)d_in[2];
  const float* d_right = (const float*)d_in[3];
  const float* bn_gamma = (const float*)d_in[4];
  const float* bn_beta = (const float*)d_in[5];
  const float* rb_w1 = (const float*)d_in[6];
  const float* rb_b1 = (const float*)d_in[7];
  const float* rb_w2 = (const float*)d_in[8];
  const float* rb_b2 = (const float*)d_in[9];
  const float* qkv_w = (const float*)d_in[10];
  const float* qkv_b = (const float*)d_in[11];

  float* ws = (float*)d_ws;
  const size_t S = S_ELEMS;
  float* buf_t = ws;             // S
  float* buf_r = ws + S;         // S
  float* kvL = ws + 2 * S;       // 2S (B,128,HW): K then V
  float* kvR = ws + 4 * S;       // 2S
  float* stats = ws + 6 * S;     // 256 floats (side-major: scale[64], shift[64])

  float* out_left = (float*)d_out;   // stages Q_left
  float* out_right = out_left + S;   // stages Q_right

  bn_stats_k<<<128, 256, 0, stream>>>(x_left, x_right, bn_gamma, bn_beta, stats);

  for (int side = 0; side < 2; ++side) {
    const float* x = side ? x_right : x_left;
    float* kv = side ? kvR : kvL;
    float* q = side ? out_right : out_left;
    const float* ss = stats + side * 128;
    conv3x3_t<true, true, false><<<2048, 256, 0, stream>>>(x, rb_w1, rb_b1, ss, nullptr, buf_t);
    conv3x3_t<false, false, true><<<2048, 256, 0, stream>>>(buf_t, rb_w2, rb_b2, ss, x, buf_r);
    qkv_k<<<1024, 256, 0, stream>>>(buf_r, qkv_w, qkv_b, q, kv);
  }
  attn_fused_k<<<4096, 256, 0, stream>>>(out_left, out_right, kvL, kvR,
                                         d_left, d_right, x_left, x_right,
                                         out_left, out_right);
}

// Round 8
// 1261.833 us; speedup vs baseline: 1.2211x; 1.2211x over previous
//
#include <hip/hip_runtime.h>
#include <cstdint>

#define HW 131072        // H*W
#define S_ELEMS 16777216 // B*C*H*W

typedef __attribute__((ext_vector_type(8))) _Float16 f16x8;
typedef __attribute__((ext_vector_type(4))) float f32x4;

__device__ __forceinline__ float h2f(unsigned short u) {
  return (float)__builtin_bit_cast(_Float16, u);
}
__device__ __forceinline__ unsigned short f2h(float f) {
  return __builtin_bit_cast(unsigned short, (_Float16)f);
}

// ---------------- BN stats (both sides): emit scale/shift ----------------
__global__ __launch_bounds__(256) void bn_stats_k(const float* __restrict__ xL,
                                                  const float* __restrict__ xR,
                                                  const float* __restrict__ gamma,
                                                  const float* __restrict__ beta,
                                                  float* __restrict__ stats) {
  int side = blockIdx.x >> 6;
  int c = blockIdx.x & 63;
  const float* x = side ? xR : xL;
  float s1 = 0.f, s2 = 0.f;
  for (int bb = 0; bb < 2; ++bb) {
    const float4* p = (const float4*)(x + ((size_t)(bb * 64 + c)) * HW);
    for (int i = threadIdx.x; i < HW / 4; i += 256) {
      float4 v = p[i];
      s1 += v.x + v.y + v.z + v.w;
      s2 += v.x * v.x + v.y * v.y + v.z * v.z + v.w * v.w;
    }
  }
  for (int m = 32; m; m >>= 1) {
    s1 += __shfl_xor(s1, m, 64);
    s2 += __shfl_xor(s2, m, 64);
  }
  __shared__ float r1[4], r2[4];
  int wv = threadIdx.x >> 6;
  if ((threadIdx.x & 63) == 0) { r1[wv] = s1; r2[wv] = s2; }
  __syncthreads();
  if (threadIdx.x == 0) {
    float t1 = r1[0] + r1[1] + r1[2] + r1[3];
    float t2 = r2[0] + r2[1] + r2[2] + r2[3];
    float mu = t1 / 262144.f;
    float var = t2 / 262144.f - mu * mu;
    float rs = rsqrtf(var + 1e-5f);
    float sc = rs * gamma[c];
    stats[side * 128 + c] = sc;
    stats[side * 128 + 64 + c] = beta[c] - mu * sc;
  }
}

// ---------------- tiled grouped 3x3 conv (8x32 tile) ----------------
template <bool BNIN, bool LEAKY, bool RES>
__global__ __launch_bounds__(256, 4) void conv3x3_t(const float* __restrict__ in,
                                                    const float* __restrict__ wgt,
                                                    const float* __restrict__ bias,
                                                    const float* __restrict__ ss,
                                                    const float* __restrict__ xres,
                                                    float* __restrict__ out) {
  __shared__ __align__(16) float sIn[16 * 10 * 36];
  __shared__ __align__(16) float sW[16 * 16 * 3 * 4];  // [o][ci][kh] float4 {w0,w1,w2,pad}
  __shared__ float sSc[16], sSh[16];
  int bid = blockIdx.x;
  int tw = bid & 15, th = (bid >> 4) & 31, g = (bid >> 9) & 3, b = bid >> 11;
  int tid = threadIdx.x;
  for (int e = tid; e < 2304; e += 256) {
    int o = e / 144, rem = e - o * 144, ci = rem / 9, k = rem - ci * 9;
    sW[((o * 16 + ci) * 3 + k / 3) * 4 + k % 3] = wgt[(g * 16 + o) * 144 + rem];
  }
  if ((BNIN || RES) && tid < 16) { sSc[tid] = ss[g * 16 + tid]; sSh[tid] = ss[64 + g * 16 + tid]; }
  // RACE FIX (root cause of rounds 3-6): sSc/sSh are written by tid<16 but read
  // by ALL threads in the staging loop below. Must barrier before reading.
  __syncthreads();
  int h0 = th * 8 - 1, w0 = tw * 32 - 1;
  const float* inb = in + ((size_t)(b * 64 + g * 16)) * HW;
  for (int e = tid; e < 5440; e += 256) {
    int ci = e / 340, rem = e - ci * 340, r = rem / 34, c = rem - r * 34;
    int h = h0 + r, w = w0 + c;
    float v = 0.f;
    if ((unsigned)h < 256u && (unsigned)w < 512u) {
      v = inb[(size_t)ci * HW + h * 512 + w];
      if (BNIN) v = v * sSc[ci] + sSh[ci];
    }
    sIn[ci * 360 + r * 36 + c] = v;
  }
  __syncthreads();
  int oh = tid >> 6;  // 0..3 output-channel quad
  int pxi = tid & 63;
  int row = pxi >> 3, col = (pxi & 7) * 4;
  float acc[4][4];
#pragma unroll
  for (int o = 0; o < 4; ++o) {
    float bz = bias[g * 16 + oh * 4 + o];
#pragma unroll
    for (int p = 0; p < 4; ++p) acc[o][p] = bz;
  }
  for (int ci = 0; ci < 16; ++ci) {
    float v[3][6];
    const float* base = sIn + ci * 360 + row * 36 + col;
#pragma unroll
    for (int kh = 0; kh < 3; ++kh) {
      float4 a4 = *(const float4*)(base + kh * 36);
      float2 a2 = *(const float2*)(base + kh * 36 + 4);
      v[kh][0] = a4.x; v[kh][1] = a4.y; v[kh][2] = a4.z; v[kh][3] = a4.w;
      v[kh][4] = a2.x; v[kh][5] = a2.y;
    }
    const float4* wb = (const float4*)sW + ((oh * 4) * 16 + ci) * 3;
#pragma unroll
    for (int o = 0; o < 4; ++o) {
      const float4* wo = wb + o * 48;
#pragma unroll
      for (int kh = 0; kh < 3; ++kh) {
        float4 wv = wo[kh];
#pragma unroll
        for (int p = 0; p < 4; ++p)
          acc[o][p] += wv.x * v[kh][p] + wv.y * v[kh][p + 1] + wv.z * v[kh][p + 2];
      }
    }
  }
  int h = th * 8 + row, wcol = tw * 32 + col;
#pragma unroll
  for (int o = 0; o < 4; ++o) {
    int cg = g * 16 + oh * 4 + o;
    size_t off = ((size_t)(b * 64 + cg)) * HW + h * 512 + wcol;
    float4 r4;
    float* rp = (float*)&r4;
    if (RES) {
      float4 x4 = *(const float4*)(xres + off);
      float sc = sSc[oh * 4 + o], sh = sSh[oh * 4 + o];
#pragma unroll
      for (int p = 0; p < 4; ++p) {
        float a = acc[o][p];
        if (LEAKY) a = a > 0.f ? a : 0.1f * a;
        rp[p] = a + ((float*)&x4)[p] * sc + sh;
      }
    } else {
#pragma unroll
      for (int p = 0; p < 4; ++p) {
        float a = acc[o][p];
        if (LEAKY) a = a > 0.f ? a : 0.1f * a;
        rp[p] = a;
      }
    }
    *(float4*)(out + off) = r4;
  }
}

// ---------------- 1x1 qkv conv: Q,K fp32 planes; V fp16 planes ----------------
__global__ __launch_bounds__(256) void qkv_k(const float* __restrict__ r,
                                             const float* __restrict__ wgt,
                                             const float* __restrict__ bias,
                                             float* __restrict__ qf,
                                             float* __restrict__ kf,
                                             unsigned short* __restrict__ vh) {
  __shared__ __align__(16) float sW[768];
  __shared__ float sB[48];
  int tid = threadIdx.x;
  int g = blockIdx.x >> 10;
  int idx = (blockIdx.x & 1023) * 256 + tid;  // over B*HW
  for (int e = tid; e < 768; e += 256) {
    int oo = e >> 4, ci = e & 15;
    sW[e] = wgt[(g * 48 + oo) * 16 + ci];
  }
  if (tid < 48) sB[tid] = bias[g * 48 + tid];
  __syncthreads();
  int p = idx & (HW - 1);
  int b = idx >> 17;
  const float* rb = r + ((size_t)(b * 64 + g * 16)) * HW + p;
  float in[16];
#pragma unroll
  for (int ci = 0; ci < 16; ++ci) in[ci] = rb[(size_t)ci * HW];
  for (int oo = 0; oo < 48; ++oo) {
    float acc = sB[oo];
    const float4* w4 = (const float4*)(sW + oo * 16);
#pragma unroll
    for (int q = 0; q < 4; ++q) {
      float4 u = w4[q];
      acc += u.x * in[q * 4] + u.y * in[q * 4 + 1] + u.z * in[q * 4 + 2] + u.w * in[q * 4 + 3];
    }
    int o = g * 48 + oo;
    if (o < 64)
      qf[((size_t)(b * 64 + o)) * HW + p] = acc;
    else if (o < 128)
      kf[((size_t)(b * 64 + o - 64)) * HW + p] = acc;
    else
      vh[((size_t)(b * 64 + o - 128)) * HW + p] = f2h(acc);
  }
}

// ---------------- fused per-window attention: split-fp16 MFMA + fp32 m-path ----------------
__global__ __launch_bounds__(256, 2) void attn_k(
    const float* qL, const float* qR,                       // fp32 Q planes (alias d_out!)
    const float* __restrict__ kL, const float* __restrict__ kR,
    const unsigned short* __restrict__ vL, const unsigned short* __restrict__ vR,
    const float* __restrict__ dL, const float* __restrict__ dR,
    const float* __restrict__ xL, const float* __restrict__ xR,
    float* outL, float* outR) {
  const int n = blockIdx.x;
  const int b = n >> 11, hb = (n >> 6) & 31, wb = n & 63;
  const int tid = threadIdx.x;
  const int lane = tid & 63, w = tid >> 6;
  const int l15 = lane & 15, lg = lane >> 4;

  // K hi/lo (stride 72 halves) — region later reused as fp32 M (stride 65 floats)
  __shared__ __align__(16) unsigned short sK[4 * 64 * 72];   // KH_A, KL_A, KH_B, KL_B
  __shared__ __align__(16) unsigned short sM[2 * 64 * 72];   // M fp16 for PV
  __shared__ float meanA[8], meanB[8], qsA[64], qsB[64], mapL[64], mapR[64];
  unsigned short* KHA = sK;
  unsigned short* KLA = sK + 64 * 72;
  unsigned short* KHB = sK + 2 * 64 * 72;
  unsigned short* KLB = sK + 3 * 64 * 72;
  unsigned short* MHA = sM;
  unsigned short* MHB = sM + 64 * 72;
  float* M32A = (float*)sK;          // [64][65]
  float* M32B = (float*)sK + 4160;   // [64][65]

  const float* dLb = dL + (size_t)b * HW;
  const float* dRb = dR + (size_t)b * HW;
  const float* kLb = kL + (size_t)b * 64 * HW;
  const float* kRb = kR + (size_t)b * 64 * HW;
  const unsigned short* vLb = vL + (size_t)b * 64 * HW;
  const unsigned short* vRb = vR + (size_t)b * 64 * HW;

  // ---- K gather into LDS, split hi/lo ----
  for (int idx = tid; idx < 4096; idx += 256) {
    int c2 = idx >> 6, k = idx & 63;
    int s = hb * 4096 + (k >> 3) * 512 + wb * 8 + (k & 7);
    int hh = 4 * c2 + (s >> 15);
    int rem = s & 32767;
    int ww = rem >> 6, cc = rem & 63;
    int dpos = hh * 512 + ww;
    int iwr = ww - (int)dLb[dpos]; iwr = min(max(iwr, 0), 511);
    int iwl = ww + (int)dRb[dpos]; iwl = min(max(iwl, 0), 511);
    size_t base = (size_t)cc * HW + hh * 512;
    float kr = kRb[base + iwr];  // Kr_sel (r2l)
    float kl_ = kLb[base + iwl]; // Kl_sel (l2r)
    unsigned short hr = f2h(kr), hl = f2h(kl_);
    KHA[k * 72 + c2] = hr; KLA[k * 72 + c2] = f2h(kr - h2f(hr));
    KHB[k * 72 + c2] = hl; KLB[k * 72 + c2] = f2h(kl_ - h2f(hl));
  }

  // ---- Q load (fp32 planes) + split ----
  const int jr = 16 * w + l15;
  const int hp = hb * 8 + (jr >> 3), wp = wb * 8 + (jr & 7);
  const int gpix = hp * 512 + wp;
  const float* qlb = qL + (size_t)b * 64 * HW + gpix;
  const float* qrb = qR + (size_t)b * 64 * HW + gpix;
  float qv0[8], qv1[8], qw0[8], qw1[8];
#pragma unroll
  for (int e = 0; e < 8; ++e) {
    qv0[e] = qlb[(size_t)(8 * lg + e) * HW];
    qv1[e] = qlb[(size_t)(32 + 8 * lg + e) * HW];
    qw0[e] = qrb[(size_t)(8 * lg + e) * HW];
    qw1[e] = qrb[(size_t)(32 + 8 * lg + e) * HW];
  }
  f16x8 qah0, qal0, qah1, qal1, qbh0, qbl0, qbh1, qbl1;
#pragma unroll
  for (int e = 0; e < 8; ++e) {
    _Float16 h;
    h = (_Float16)qv0[e]; qah0[e] = h; qal0[e] = (_Float16)(qv0[e] - (float)h);
    h = (_Float16)qv1[e]; qah1[e] = h; qal1[e] = (_Float16)(qv1[e] - (float)h);
    h = (_Float16)qw0[e]; qbh0[e] = h; qbl0[e] = (_Float16)(qw0[e] - (float)h);
    h = (_Float16)qw1[e]; qbh1[e] = h; qbl1[e] = (_Float16)(qw1[e] - (float)h);
  }

  // ---- V fragments (registers, fp16 planes) ----
  uint32_t vAr[2][4], vBr[2][4];
  {
    const int cv = 16 * w + l15;
#pragma unroll
    for (int h = 0; h < 2; ++h) {
      int hi = 4 * h + lg;
      int hh = 4 * cv + (hb >> 3);
      int ww = (hb & 7) * 64 + hi * 8 + (wb >> 3);
      int dpos = hh * 512 + ww;
      int iwr = ww - (int)dLb[dpos]; iwr = min(max(iwr, 0), 511);
      int iwl = ww + (int)dRb[dpos]; iwl = min(max(iwl, 0), 511);
      unsigned short er[8], el[8];
#pragma unroll
      for (int wi = 0; wi < 8; ++wi) {
        int cc = (wb & 7) * 8 + wi;
        size_t base = (size_t)cc * HW + hh * 512;
        er[wi] = vRb[base + iwr];
        el[wi] = vLb[base + iwl];
      }
#pragma unroll
      for (int q = 0; q < 4; ++q) {
        vAr[h][q] = (uint32_t)er[2 * q] | ((uint32_t)er[2 * q + 1] << 16);
        vBr[h][q] = (uint32_t)el[2 * q] | ((uint32_t)el[2 * q + 1] << 16);
      }
    }
  }
  __syncthreads();  // B1: K staged

  // ---- K means per (dir,hi) over (wi,c): exact = hi+lo ----
  {
    int grp = tid >> 4, i = tid & 15;
    int dir = grp >> 3, hi = grp & 7;
    int off0 = (8 * hi + (i >> 1)) * 72 + (i & 1) * 32;
    const unsigned short* srcH = (dir ? KHB : KHA) + off0;
    const unsigned short* srcL = (dir ? KLB : KLA) + off0;
    float s = 0.f;
#pragma unroll
    for (int q = 0; q < 32; ++q) s += h2f(srcH[q]) + h2f(srcL[q]);
    for (int m = 8; m; m >>= 1) s += __shfl_xor(s, m, 64);
    if (i == 0) (dir ? meanB : meanA)[hi] = s * (1.f / 512.f);
  }
  // ---- qsum[j] (fp32 exact) ----
  {
    float sa = 0.f, sb = 0.f;
#pragma unroll
    for (int e = 0; e < 8; ++e) {
      sa += qv0[e] + qv1[e];
      sb += qw0[e] + qw1[e];
    }
    sa += __shfl_xor(sa, 16, 64); sa += __shfl_xor(sa, 32, 64);
    sb += __shfl_xor(sb, 16, 64); sb += __shfl_xor(sb, 32, 64);
    if (lane < 16) { qsA[jr] = sa; qsB[jr] = sb; }
  }
  __syncthreads();  // B2: means + qsums ready

  // ---- QK^T via split-fp16 MFMA: q.k ~= qh.kh + qh.kl + ql.kh ----
  f32x4 sA[4], sB[4];
#pragma unroll
  for (int t = 0; t < 4; ++t) { sA[t] = (f32x4){0.f, 0.f, 0.f, 0.f}; sB[t] = sA[t]; }
#pragma unroll
  for (int t = 0; t < 4; ++t) {
    int ro = (16 * t + l15) * 72 + 8 * lg;
    f16x8 kh0 = *(const f16x8*)(KHA + ro);
    f16x8 kl0 = *(const f16x8*)(KLA + ro);
    f16x8 kh1 = *(const f16x8*)(KHA + ro + 32);
    f16x8 kl1 = *(const f16x8*)(KLA + ro + 32);
    sA[t] = __builtin_amdgcn_mfma_f32_16x16x32_f16(qah0, kh0, sA[t], 0, 0, 0);
    sA[t] = __builtin_amdgcn_mfma_f32_16x16x32_f16(qah0, kl0, sA[t], 0, 0, 0);
    sA[t] = __builtin_amdgcn_mfma_f32_16x16x32_f16(qal0, kh0, sA[t], 0, 0, 0);
    sA[t] = __builtin_amdgcn_mfma_f32_16x16x32_f16(qah1, kh1, sA[t], 0, 0, 0);
    sA[t] = __builtin_amdgcn_mfma_f32_16x16x32_f16(qah1, kl1, sA[t], 0, 0, 0);
    sA[t] = __builtin_amdgcn_mfma_f32_16x16x32_f16(qal1, kh1, sA[t], 0, 0, 0);
    f16x8 mh0 = *(const f16x8*)(KHB + ro);
    f16x8 ml0 = *(const f16x8*)(KLB + ro);
    f16x8 mh1 = *(const f16x8*)(KHB + ro + 32);
    f16x8 ml1 = *(const f16x8*)(KLB + ro + 32);
    sB[t] = __builtin_amdgcn_mfma_f32_16x16x32_f16(qbh0, mh0, sB[t], 0, 0, 0);
    sB[t] = __builtin_amdgcn_mfma_f32_16x16x32_f16(qbh0, ml0, sB[t], 0, 0, 0);
    sB[t] = __builtin_amdgcn_mfma_f32_16x16x32_f16(qbl0, mh0, sB[t], 0, 0, 0);
    sB[t] = __builtin_amdgcn_mfma_f32_16x16x32_f16(qbh1, mh1, sB[t], 0, 0, 0);
    sB[t] = __builtin_amdgcn_mfma_f32_16x16x32_f16(qbh1, ml1, sB[t], 0, 0, 0);
    sB[t] = __builtin_amdgcn_mfma_f32_16x16x32_f16(qbl1, mh1, sB[t], 0, 0, 0);
  }
  // ---- mean-fold correction + in-register softmax over k ----
  {
    float qra[4], qrb2[4];
#pragma unroll
    for (int reg = 0; reg < 4; ++reg) {
      qra[reg] = qsA[16 * w + 4 * lg + reg];
      qrb2[reg] = qsB[16 * w + 4 * lg + reg];
    }
#pragma unroll
    for (int t = 0; t < 4; ++t) {
      float mA_ = meanA[2 * t + (l15 >> 3)];
      float mB_ = meanB[2 * t + (l15 >> 3)];
#pragma unroll
      for (int reg = 0; reg < 4; ++reg) {
        sA[t][reg] -= qra[reg] * mA_;
        sB[t][reg] -= qrb2[reg] * mB_;
      }
    }
#pragma unroll
    for (int reg = 0; reg < 4; ++reg) {
      float ma = sA[0][reg], mb = sB[0][reg];
#pragma unroll
      for (int t = 1; t < 4; ++t) { ma = fmaxf(ma, sA[t][reg]); mb = fmaxf(mb, sB[t][reg]); }
#pragma unroll
      for (int m = 1; m <= 8; m <<= 1) {
        ma = fmaxf(ma, __shfl_xor(ma, m, 64));
        mb = fmaxf(mb, __shfl_xor(mb, m, 64));
      }
      float sa = 0.f, sb = 0.f;
#pragma unroll
      for (int t = 0; t < 4; ++t) {
        float ea = __expf(sA[t][reg] - ma), eb = __expf(sB[t][reg] - mb);
        sA[t][reg] = ea; sB[t][reg] = eb;
        sa += ea; sb += eb;
      }
#pragma unroll
      for (int m = 1; m <= 8; m <<= 1) {
        sa += __shfl_xor(sa, m, 64);
        sb += __shfl_xor(sb, m, 64);
      }
      float ra = 1.f / sa, rb = 1.f / sb;
#pragma unroll
      for (int t = 0; t < 4; ++t) { sA[t][reg] *= ra; sB[t][reg] *= rb; }
    }
  }
  __syncthreads();  // B2.5: all K reads done; safe to overlay M32 onto K region

  // ---- write M: fp16 (PV) + fp32 (m-map path) ----
#pragma unroll
  for (int t = 0; t < 4; ++t)
#pragma unroll
    for (int reg = 0; reg < 4; ++reg) {
      int jrow = 16 * w + 4 * lg + reg, kcol = 16 * t + l15;
      MHA[jrow * 72 + kcol] = f2h(sA[t][reg]);
      MHB[jrow * 72 + kcol] = f2h(sB[t][reg]);
      M32A[jrow * 65 + kcol] = sA[t][reg];
      M32B[jrow * 65 + kcol] = sB[t][reg];
    }
  __syncthreads();  // B3: M complete

  // ---- PV via MFMA (fp16): X^T[c][j] = sum_k V_sel[k][c] * M[j][k] ----
  f32x4 pL[4], pR[4];
#pragma unroll
  for (int t = 0; t < 4; ++t) { pL[t] = (f32x4){0.f, 0.f, 0.f, 0.f}; pR[t] = pL[t]; }
#pragma unroll
  for (int h = 0; h < 2; ++h) {
    f16x8 va = __builtin_bit_cast(f16x8, *(const int4*)&vAr[h][0]);
    f16x8 vb = __builtin_bit_cast(f16x8, *(const int4*)&vBr[h][0]);
#pragma unroll
    for (int jt = 0; jt < 4; ++jt) {
      f16x8 ma = *(const f16x8*)(MHA + (16 * jt + l15) * 72 + 32 * h + 8 * lg);
      f16x8 mb = *(const f16x8*)(MHB + (16 * jt + l15) * 72 + 32 * h + 8 * lg);
      pL[jt] = __builtin_amdgcn_mfma_f32_16x16x32_f16(va, ma, pL[jt], 0, 0, 0);
      pR[jt] = __builtin_amdgcn_mfma_f32_16x16x32_f16(vb, mb, pR[jt], 0, 0, 0);
    }
  }
  // ---- m_relax band + einsum + tanh from fp32 M (128 threads) ----
  if (tid < 128) {
    int dir = tid >> 6, j = tid & 63;
    const float* Mrow = dir ? M32B : M32A;
    const float* Mcol = dir ? M32A : M32B;
    float acc = 0.f;
    for (int k = 0; k < 64; ++k) {
      float rx = 0.f;
#pragma unroll
      for (int i = -2; i <= 2; ++i) {
        int jj = j + i;
        if ((unsigned)jj < 64u) rx += Mrow[jj * 65 + k];
      }
      acc += rx * Mcol[k * 65 + j];
    }
    (dir ? mapR : mapL)[j] = tanhf(5.f * acc);
  }
  __syncthreads();  // B4: maps ready

  // ---- blend + store ----
#pragma unroll
  for (int jt = 0; jt < 4; ++jt) {
#pragma unroll
    for (int reg = 0; reg < 4; ++reg) {
      int c = 16 * w + 4 * lg + reg;
      int j = 16 * jt + l15;
      int hp2 = hb * 8 + (j >> 3), wp2 = wb * 8 + (j & 7);
      size_t off = ((size_t)(b * 64 + c)) * HW + hp2 * 512 + wp2;
      float ml = mapL[j], mr = mapR[j];
      outL[off] = xL[off] * (1.f - ml) + pL[jt][reg] * ml;
      outR[off] = xR[off] * (1.f - mr) + pR[jt][reg] * mr;
    }
  }
}

extern "C" void kernel_launch(void* const* d_in, const int* in_sizes, int n_in,
                              void* d_out, int out_size, void* d_ws, size_t ws_size,
                              hipStream_t stream) {
  const float* x_left = (const float*)d_in[0];
  const float* x_right = (const float*)d_in[1];
  const float* d_left = (const float*)d_in[2];
  const float* d_right = (const float*)d_in[3];
  const float* bn_gamma = (const float*)d_in[4];
  const float* bn_beta = (const float*)d_in[5];
  const float* rb_w1 = (const float*)d_in[6];
  const float* rb_b1 = (const float*)d_in[7];
  const float* rb_w2 = (const float*)d_in[8];
  const float* rb_b2 = (const float*)d_in[9];
  const float* qkv_w = (const float*)d_in[10];
  const float* qkv_b = (const float*)d_in[11];

  float* ws = (float*)d_ws;
  const size_t S = S_ELEMS;
  float* buf_t = ws;                 // S floats
  float* buf_r = ws + S;             // S floats
  float* kfL = ws + 2 * S;           // S floats (B,64,HW)
  float* kfR = ws + 3 * S;           // S floats
  unsigned short* vhL = (unsigned short*)(ws + 4 * S);   // S ushorts
  unsigned short* vhR = vhL + S;                         // S ushorts
  float* stats = (float*)(vhR + S);  // 256 floats

  float* out_left = (float*)d_out;   // stages Q_left (fp32 planes)
  float* out_right = out_left + S;   // stages Q_right

  bn_stats_k<<<128, 256, 0, stream>>>(x_left, x_right, bn_gamma, bn_beta, stats);

  for (int side = 0; side < 2; ++side) {
    const float* x = side ? x_right : x_left;
    float* qf = side ? out_right : out_left;
    float* kf = side ? kfR : kfL;
    unsigned short* vh = side ? vhR : vhL;
    const float* ss = stats + side * 128;
    conv3x3_t<true, true, false><<<4096, 256, 0, stream>>>(x, rb_w1, rb_b1, ss, nullptr, buf_t);
    conv3x3_t<false, false, true><<<4096, 256, 0, stream>>>(buf_t, rb_w2, rb_b2, ss, x, buf_r);
    qkv_k<<<4096, 256, 0, stream>>>(buf_r, qkv_w, qkv_b, qf, kf, vh);
  }
  attn_k<<<4096, 256, 0, stream>>>(out_left, out_right, kfL, kfR, vhL, vhR,
                                   d_left, d_right, x_left, x_right,
                                   out_left, out_right);
}

// Round 9
// 1172.691 us; speedup vs baseline: 1.3139x; 1.0760x over previous
//
#include <hip/hip_runtime.h>
#include <cstdint>

#define HW 131072        // H*W
#define S_ELEMS 16777216 // B*C*H*W

typedef __attribute__((ext_vector_type(8))) _Float16 f16x8;
typedef __attribute__((ext_vector_type(4))) float f32x4;

__device__ __forceinline__ float h2f(unsigned short u) {
  return (float)__builtin_bit_cast(_Float16, u);
}
__device__ __forceinline__ unsigned short f2h(float f) {
  return __builtin_bit_cast(unsigned short, (_Float16)f);
}

// ---------------- BN stats stage 1: partial sums (2 sides x 64 c x 16 slabs) ----------------
__global__ __launch_bounds__(256) void bn_part_k(const float* __restrict__ xL,
                                                 const float* __restrict__ xR,
                                                 float2* __restrict__ partial) {
  int bid = blockIdx.x;
  int side = bid >> 10, rest = bid & 1023;
  int c = rest >> 4, sl = rest & 15;
  const float* x = side ? xR : xL;
  const float4* p = (const float4*)(x + ((size_t)((sl >> 3) * 64 + c)) * HW + (size_t)(sl & 7) * 16384);
  float s1 = 0.f, s2 = 0.f;
  for (int i = threadIdx.x; i < 4096; i += 256) {
    float4 v = p[i];
    s1 += v.x + v.y + v.z + v.w;
    s2 += v.x * v.x + v.y * v.y + v.z * v.z + v.w * v.w;
  }
  for (int m = 32; m; m >>= 1) {
    s1 += __shfl_xor(s1, m, 64);
    s2 += __shfl_xor(s2, m, 64);
  }
  __shared__ float r1[4], r2[4];
  int wv = threadIdx.x >> 6;
  if ((threadIdx.x & 63) == 0) { r1[wv] = s1; r2[wv] = s2; }
  __syncthreads();
  if (threadIdx.x == 0) {
    partial[bid] = make_float2(r1[0] + r1[1] + r1[2] + r1[3], r2[0] + r2[1] + r2[2] + r2[3]);
  }
}

// ---------------- BN stats stage 2: finalize scale/shift ----------------
__global__ __launch_bounds__(128) void bn_fin_k(const float2* __restrict__ partial,
                                                const float* __restrict__ gamma,
                                                const float* __restrict__ beta,
                                                float* __restrict__ stats) {
  int tid = threadIdx.x;  // 0..127: side*64 + c
  int side = tid >> 6, c = tid & 63;
  float s1 = 0.f, s2 = 0.f;
  const float2* p = partial + (side * 1024 + c * 16);
  for (int s = 0; s < 16; ++s) { float2 v = p[s]; s1 += v.x; s2 += v.y; }
  float mu = s1 / 262144.f;
  float var = s2 / 262144.f - mu * mu;
  float rs = rsqrtf(var + 1e-5f);
  float sc = rs * gamma[c];
  stats[side * 128 + c] = sc;
  stats[side * 128 + 64 + c] = beta[c] - mu * sc;
}

// ---------------- tiled grouped 3x3 conv (8x32 tile) ----------------
template <bool BNIN, bool LEAKY, bool RES>
__global__ __launch_bounds__(256, 4) void conv3x3_t(const float* __restrict__ in,
                                                    const float* __restrict__ wgt,
                                                    const float* __restrict__ bias,
                                                    const float* __restrict__ ss,
                                                    const float* __restrict__ xres,
                                                    float* __restrict__ out) {
  __shared__ __align__(16) float sIn[16 * 10 * 36];
  __shared__ __align__(16) float sW[16 * 16 * 3 * 4];  // [o][ci][kh] float4 {w0,w1,w2,pad}
  __shared__ float sSc[16], sSh[16];
  int bid = blockIdx.x;
  int tw = bid & 15, th = (bid >> 4) & 31, g = (bid >> 9) & 3, b = bid >> 11;
  int tid = threadIdx.x;
  for (int e = tid; e < 2304; e += 256) {
    int o = e / 144, rem = e - o * 144, ci = rem / 9, k = rem - ci * 9;
    sW[((o * 16 + ci) * 3 + k / 3) * 4 + k % 3] = wgt[(g * 16 + o) * 144 + rem];
  }
  if ((BNIN || RES) && tid < 16) { sSc[tid] = ss[g * 16 + tid]; sSh[tid] = ss[64 + g * 16 + tid]; }
  // RACE FIX: sSc/sSh written by tid<16, read by all in staging loop.
  __syncthreads();
  int h0 = th * 8 - 1, w0 = tw * 32 - 1;
  const float* inb = in + ((size_t)(b * 64 + g * 16)) * HW;
  for (int e = tid; e < 5440; e += 256) {
    int ci = e / 340, rem = e - ci * 340, r = rem / 34, c = rem - r * 34;
    int h = h0 + r, w = w0 + c;
    float v = 0.f;
    if ((unsigned)h < 256u && (unsigned)w < 512u) {
      v = inb[(size_t)ci * HW + h * 512 + w];
      if (BNIN) v = v * sSc[ci] + sSh[ci];
    }
    sIn[ci * 360 + r * 36 + c] = v;
  }
  __syncthreads();
  int oh = tid >> 6;  // 0..3 output-channel quad
  int pxi = tid & 63;
  int row = pxi >> 3, col = (pxi & 7) * 4;
  float acc[4][4];
#pragma unroll
  for (int o = 0; o < 4; ++o) {
    float bz = bias[g * 16 + oh * 4 + o];
#pragma unroll
    for (int p = 0; p < 4; ++p) acc[o][p] = bz;
  }
  for (int ci = 0; ci < 16; ++ci) {
    float v[3][6];
    const float* base = sIn + ci * 360 + row * 36 + col;
#pragma unroll
    for (int kh = 0; kh < 3; ++kh) {
      float4 a4 = *(const float4*)(base + kh * 36);
      float2 a2 = *(const float2*)(base + kh * 36 + 4);
      v[kh][0] = a4.x; v[kh][1] = a4.y; v[kh][2] = a4.z; v[kh][3] = a4.w;
      v[kh][4] = a2.x; v[kh][5] = a2.y;
    }
    const float4* wb = (const float4*)sW + ((oh * 4) * 16 + ci) * 3;
#pragma unroll
    for (int o = 0; o < 4; ++o) {
      const float4* wo = wb + o * 48;
#pragma unroll
      for (int kh = 0; kh < 3; ++kh) {
        float4 wv = wo[kh];
#pragma unroll
        for (int p = 0; p < 4; ++p)
          acc[o][p] += wv.x * v[kh][p] + wv.y * v[kh][p + 1] + wv.z * v[kh][p + 2];
      }
    }
  }
  int h = th * 8 + row, wcol = tw * 32 + col;
#pragma unroll
  for (int o = 0; o < 4; ++o) {
    int cg = g * 16 + oh * 4 + o;
    size_t off = ((size_t)(b * 64 + cg)) * HW + h * 512 + wcol;
    float4 r4;
    float* rp = (float*)&r4;
    if (RES) {
      float4 x4 = *(const float4*)(xres + off);
      float sc = sSc[oh * 4 + o], sh = sSh[oh * 4 + o];
#pragma unroll
      for (int p = 0; p < 4; ++p) {
        float a = acc[o][p];
        if (LEAKY) a = a > 0.f ? a : 0.1f * a;
        rp[p] = a + ((float*)&x4)[p] * sc + sh;
      }
    } else {
#pragma unroll
      for (int p = 0; p < 4; ++p) {
        float a = acc[o][p];
        if (LEAKY) a = a > 0.f ? a : 0.1f * a;
        rp[p] = a;
      }
    }
    *(float4*)(out + off) = r4;
  }
}

// ---------------- 1x1 qkv conv: Q fp32 planes; K NHWC fp32 [pix][64]; V NHWC fp16 [pix][64] --
__global__ __launch_bounds__(256) void qkv_k(const float* __restrict__ r,
                                             const float* __restrict__ wgt,
                                             const float* __restrict__ bias,
                                             float* __restrict__ qf,
                                             float* __restrict__ kn,
                                             unsigned short* __restrict__ vn) {
  __shared__ __align__(16) float sW[768];
  __shared__ float sB[48];
  int tid = threadIdx.x;
  int g = blockIdx.x >> 10;
  int idx = (blockIdx.x & 1023) * 256 + tid;  // over B*HW
  for (int e = tid; e < 768; e += 256) {
    int oo = e >> 4, ci = e & 15;
    sW[e] = wgt[(g * 48 + oo) * 16 + ci];
  }
  if (tid < 48) sB[tid] = bias[g * 48 + tid];
  __syncthreads();
  int p = idx & (HW - 1);
  int b = idx >> 17;
  const float* rb = r + ((size_t)(b * 64 + g * 16)) * HW + p;
  float in[16];
#pragma unroll
  for (int ci = 0; ci < 16; ++ci) in[ci] = rb[(size_t)ci * HW];
  size_t pxbase = ((size_t)b * HW + p) * 64;
  for (int oo = 0; oo < 48; oo += 4) {
    float a[4];
#pragma unroll
    for (int j = 0; j < 4; ++j) {
      float acc = sB[oo + j];
      const float4* w4 = (const float4*)(sW + (oo + j) * 16);
#pragma unroll
      for (int q = 0; q < 4; ++q) {
        float4 u = w4[q];
        acc += u.x * in[q * 4] + u.y * in[q * 4 + 1] + u.z * in[q * 4 + 2] + u.w * in[q * 4 + 3];
      }
      a[j] = acc;
    }
    int o = g * 48 + oo;
    if (o < 64) {
#pragma unroll
      for (int j = 0; j < 4; ++j) qf[((size_t)(b * 64 + o + j)) * HW + p] = a[j];
    } else if (o < 128) {
      *(float4*)(kn + pxbase + (o - 64)) = *(float4*)a;
    } else {
      uint2 pk;
      pk.x = (uint32_t)f2h(a[0]) | ((uint32_t)f2h(a[1]) << 16);
      pk.y = (uint32_t)f2h(a[2]) | ((uint32_t)f2h(a[3]) << 16);
      *(uint2*)(vn + pxbase + (o - 128)) = pk;
    }
  }
}

// ---------------- fused per-window attention: split-fp16 MFMA, NHWC gathers, 4 blocks/CU ----
__global__ __launch_bounds__(256, 4) void attn_k(
    const float* qL, const float* qR,                       // fp32 Q planes (alias d_out!)
    const float* __restrict__ kLn, const float* __restrict__ kRn,   // NHWC fp32
    const unsigned short* __restrict__ vLn, const unsigned short* __restrict__ vRn, // NHWC fp16
    const float* __restrict__ dL, const float* __restrict__ dR,
    const float* __restrict__ xL, const float* __restrict__ xR,
    float* outL, float* outR) {
  const int n = blockIdx.x;
  const int b = n >> 11, hb = (n >> 6) & 31, wb = n & 63;
  const int tid = threadIdx.x;
  const int lane = tid & 63, w = tid >> 6;
  const int l15 = lane & 15, lg = lane >> 4;

  // K hi/lo (stride 72, fp16) — region reused after QK^T as fp32 M (stride 68)
  __shared__ __align__(16) unsigned short sK[4 * 64 * 72];   // 36864 B
  __shared__ float meanA[8], meanB[8], qsA[64], qsB[64], mapL[64], mapR[64];
  unsigned short* KHA = sK;
  unsigned short* KLA = sK + 64 * 72;
  unsigned short* KHB = sK + 2 * 64 * 72;
  unsigned short* KLB = sK + 3 * 64 * 72;
  float* M32A = (float*)sK;           // [64][68] = 17408 B
  float* M32B = (float*)sK + 64 * 68; // [64][68]

  const float* dLb = dL + (size_t)b * HW;
  const float* dRb = dR + (size_t)b * HW;
  const size_t nb = (size_t)b * HW;

  // ---- K gather (NHWC): 2 iters, 8 channels per thread per dir ----
  const int cc0 = (wb & 7) * 8;
#pragma unroll
  for (int it = 0; it < 2; ++it) {
    int slot = tid + 256 * it;           // 0..511
    int c2 = slot & 63, k8 = slot >> 6;  // k8 0..7
    int hh = 4 * c2 + (hb >> 3);
    int ww = (hb & 7) * 64 + k8 * 8 + (wb >> 3);
    int dpos = hh * 512 + ww;
    int iwr = ww - (int)dLb[dpos]; iwr = min(max(iwr, 0), 511);
    int iwl = ww + (int)dRb[dpos]; iwl = min(max(iwl, 0), 511);
    const float* pr = kRn + (nb + hh * 512 + iwr) * 64 + cc0;
    const float* pl = kLn + (nb + hh * 512 + iwl) * 64 + cc0;
    float fr[8], fl[8];
    *(float4*)&fr[0] = *(const float4*)pr;
    *(float4*)&fr[4] = *(const float4*)(pr + 4);
    *(float4*)&fl[0] = *(const float4*)pl;
    *(float4*)&fl[4] = *(const float4*)(pl + 4);
#pragma unroll
    for (int kl = 0; kl < 8; ++kl) {
      int k = 8 * k8 + kl;
      unsigned short hr = f2h(fr[kl]), hl = f2h(fl[kl]);
      KHA[k * 72 + c2] = hr; KLA[k * 72 + c2] = f2h(fr[kl] - h2f(hr));
      KHB[k * 72 + c2] = hl; KLB[k * 72 + c2] = f2h(fl[kl] - h2f(hl));
    }
  }

  // ---- Q load (fp32 planes) + hi/lo split ----
  const int jr = 16 * w + l15;
  const int hp = hb * 8 + (jr >> 3), wp = wb * 8 + (jr & 7);
  const int gpix = hp * 512 + wp;
  const float* qlb = qL + nb * 64 + gpix;
  const float* qrb = qR + nb * 64 + gpix;
  float qv0[8], qv1[8], qw0[8], qw1[8];
#pragma unroll
  for (int e = 0; e < 8; ++e) {
    qv0[e] = qlb[(size_t)(8 * lg + e) * HW];
    qv1[e] = qlb[(size_t)(32 + 8 * lg + e) * HW];
    qw0[e] = qrb[(size_t)(8 * lg + e) * HW];
    qw1[e] = qrb[(size_t)(32 + 8 * lg + e) * HW];
  }
  f16x8 qah0, qal0, qah1, qal1, qbh0, qbl0, qbh1, qbl1;
#pragma unroll
  for (int e = 0; e < 8; ++e) {
    _Float16 h;
    h = (_Float16)qv0[e]; qah0[e] = h; qal0[e] = (_Float16)(qv0[e] - (float)h);
    h = (_Float16)qv1[e]; qah1[e] = h; qal1[e] = (_Float16)(qv1[e] - (float)h);
    h = (_Float16)qw0[e]; qbh0[e] = h; qbl0[e] = (_Float16)(qw0[e] - (float)h);
    h = (_Float16)qw1[e]; qbh1[e] = h; qbl1[e] = (_Float16)(qw1[e] - (float)h);
  }

  // ---- V fragments (NHWC fp16: one b128 per (h,dir)) ----
  int4 vAr[2], vBr[2];
  {
    const int cv = 16 * w + l15;
#pragma unroll
    for (int h = 0; h < 2; ++h) {
      int hi = 4 * h + lg;
      int hh = 4 * cv + (hb >> 3);
      int ww = (hb & 7) * 64 + hi * 8 + (wb >> 3);
      int dpos = hh * 512 + ww;
      int iwr = ww - (int)dLb[dpos]; iwr = min(max(iwr, 0), 511);
      int iwl = ww + (int)dRb[dpos]; iwl = min(max(iwl, 0), 511);
      vAr[h] = *(const int4*)(vRn + (nb + hh * 512 + iwr) * 64 + cc0);
      vBr[h] = *(const int4*)(vLn + (nb + hh * 512 + iwl) * 64 + cc0);
    }
  }
  __syncthreads();  // B1: K staged

  // ---- K means per (dir,hi) over (wi,c): exact = hi+lo ----
  {
    int grp = tid >> 4, i = tid & 15;
    int dir = grp >> 3, hi = grp & 7;
    int off0 = (8 * hi + (i >> 1)) * 72 + (i & 1) * 32;
    const unsigned short* srcH = (dir ? KHB : KHA) + off0;
    const unsigned short* srcL = (dir ? KLB : KLA) + off0;
    float s = 0.f;
#pragma unroll
    for (int q = 0; q < 32; ++q) s += h2f(srcH[q]) + h2f(srcL[q]);
    for (int m = 8; m; m >>= 1) s += __shfl_xor(s, m, 64);
    if (i == 0) (dir ? meanB : meanA)[hi] = s * (1.f / 512.f);
  }
  // ---- qsum[j] (fp32 exact) ----
  {
    float sa = 0.f, sb = 0.f;
#pragma unroll
    for (int e = 0; e < 8; ++e) {
      sa += qv0[e] + qv1[e];
      sb += qw0[e] + qw1[e];
    }
    sa += __shfl_xor(sa, 16, 64); sa += __shfl_xor(sa, 32, 64);
    sb += __shfl_xor(sb, 16, 64); sb += __shfl_xor(sb, 32, 64);
    if (lane < 16) { qsA[jr] = sa; qsB[jr] = sb; }
  }
  __syncthreads();  // B2: means + qsums ready

  // ---- QK^T via split-fp16 MFMA: q.k ~= qh.kh + qh.kl + ql.kh ----
  f32x4 sA[4], sB[4];
#pragma unroll
  for (int t = 0; t < 4; ++t) { sA[t] = (f32x4){0.f, 0.f, 0.f, 0.f}; sB[t] = sA[t]; }
#pragma unroll
  for (int t = 0; t < 4; ++t) {
    int ro = (16 * t + l15) * 72 + 8 * lg;
    f16x8 kh0 = *(const f16x8*)(KHA + ro);
    f16x8 kl0 = *(const f16x8*)(KLA + ro);
    f16x8 kh1 = *(const f16x8*)(KHA + ro + 32);
    f16x8 kl1 = *(const f16x8*)(KLA + ro + 32);
    sA[t] = __builtin_amdgcn_mfma_f32_16x16x32_f16(qah0, kh0, sA[t], 0, 0, 0);
    sA[t] = __builtin_amdgcn_mfma_f32_16x16x32_f16(qah0, kl0, sA[t], 0, 0, 0);
    sA[t] = __builtin_amdgcn_mfma_f32_16x16x32_f16(qal0, kh0, sA[t], 0, 0, 0);
    sA[t] = __builtin_amdgcn_mfma_f32_16x16x32_f16(qah1, kh1, sA[t], 0, 0, 0);
    sA[t] = __builtin_amdgcn_mfma_f32_16x16x32_f16(qah1, kl1, sA[t], 0, 0, 0);
    sA[t] = __builtin_amdgcn_mfma_f32_16x16x32_f16(qal1, kh1, sA[t], 0, 0, 0);
    f16x8 mh0 = *(const f16x8*)(KHB + ro);
    f16x8 ml0 = *(const f16x8*)(KLB + ro);
    f16x8 mh1 = *(const f16x8*)(KHB + ro + 32);
    f16x8 ml1 = *(const f16x8*)(KLB + ro + 32);
    sB[t] = __builtin_amdgcn_mfma_f32_16x16x32_f16(qbh0, mh0, sB[t], 0, 0, 0);
    sB[t] = __builtin_amdgcn_mfma_f32_16x16x32_f16(qbh0, ml0, sB[t], 0, 0, 0);
    sB[t] = __builtin_amdgcn_mfma_f32_16x16x32_f16(qbl0, mh0, sB[t], 0, 0, 0);
    sB[t] = __builtin_amdgcn_mfma_f32_16x16x32_f16(qbh1, mh1, sB[t], 0, 0, 0);
    sB[t] = __builtin_amdgcn_mfma_f32_16x16x32_f16(qbh1, ml1, sB[t], 0, 0, 0);
    sB[t] = __builtin_amdgcn_mfma_f32_16x16x32_f16(qbl1, mh1, sB[t], 0, 0, 0);
  }
  // ---- mean-fold correction + in-register softmax over k ----
  {
    float qra[4], qrb2[4];
#pragma unroll
    for (int reg = 0; reg < 4; ++reg) {
      qra[reg] = qsA[16 * w + 4 * lg + reg];
      qrb2[reg] = qsB[16 * w + 4 * lg + reg];
    }
#pragma unroll
    for (int t = 0; t < 4; ++t) {
      float mA_ = meanA[2 * t + (l15 >> 3)];
      float mB_ = meanB[2 * t + (l15 >> 3)];
#pragma unroll
      for (int reg = 0; reg < 4; ++reg) {
        sA[t][reg] -= qra[reg] * mA_;
        sB[t][reg] -= qrb2[reg] * mB_;
      }
    }
#pragma unroll
    for (int reg = 0; reg < 4; ++reg) {
      float ma = sA[0][reg], mb = sB[0][reg];
#pragma unroll
      for (int t = 1; t < 4; ++t) { ma = fmaxf(ma, sA[t][reg]); mb = fmaxf(mb, sB[t][reg]); }
#pragma unroll
      for (int m = 1; m <= 8; m <<= 1) {
        ma = fmaxf(ma, __shfl_xor(ma, m, 64));
        mb = fmaxf(mb, __shfl_xor(mb, m, 64));
      }
      float sa = 0.f, sb = 0.f;
#pragma unroll
      for (int t = 0; t < 4; ++t) {
        float ea = __expf(sA[t][reg] - ma), eb = __expf(sB[t][reg] - mb);
        sA[t][reg] = ea; sB[t][reg] = eb;
        sa += ea; sb += eb;
      }
#pragma unroll
      for (int m = 1; m <= 8; m <<= 1) {
        sa += __shfl_xor(sa, m, 64);
        sb += __shfl_xor(sb, m, 64);
      }
      float ra = 1.f / sa, rb = 1.f / sb;
#pragma unroll
      for (int t = 0; t < 4; ++t) { sA[t][reg] *= ra; sB[t][reg] *= rb; }
    }
  }
  __syncthreads();  // B2.5: all K reads done; overlay M32 onto K region

  // ---- write M fp32 (stride 68; serves both PV and m-map path) ----
#pragma unroll
  for (int t = 0; t < 4; ++t)
#pragma unroll
    for (int reg = 0; reg < 4; ++reg) {
      int jrow = 16 * w + 4 * lg + reg, kcol = 16 * t + l15;
      M32A[jrow * 68 + kcol] = sA[t][reg];
      M32B[jrow * 68 + kcol] = sB[t][reg];
    }
  __syncthreads();  // B3: M complete

  // ---- PV via MFMA (fp16 cvt from fp32 M): X^T[c][j] = sum_k V_sel[k][c] * M[j][k] ----
  f32x4 pL[4], pR[4];
#pragma unroll
  for (int t = 0; t < 4; ++t) { pL[t] = (f32x4){0.f, 0.f, 0.f, 0.f}; pR[t] = pL[t]; }
#pragma unroll
  for (int h = 0; h < 2; ++h) {
    f16x8 va = __builtin_bit_cast(f16x8, vAr[h]);
    f16x8 vb = __builtin_bit_cast(f16x8, vBr[h]);
#pragma unroll
    for (int jt = 0; jt < 4; ++jt) {
      const float* mra = M32A + (16 * jt + l15) * 68 + 32 * h + 8 * lg;
      const float* mrb = M32B + (16 * jt + l15) * 68 + 32 * h + 8 * lg;
      float fa[8], fb[8];
      *(float4*)&fa[0] = *(const float4*)mra;
      *(float4*)&fa[4] = *(const float4*)(mra + 4);
      *(float4*)&fb[0] = *(const float4*)mrb;
      *(float4*)&fb[4] = *(const float4*)(mrb + 4);
      f16x8 ma, mb;
#pragma unroll
      for (int e = 0; e < 8; ++e) { ma[e] = (_Float16)fa[e]; mb[e] = (_Float16)fb[e]; }
      pL[jt] = __builtin_amdgcn_mfma_f32_16x16x32_f16(va, ma, pL[jt], 0, 0, 0);
      pR[jt] = __builtin_amdgcn_mfma_f32_16x16x32_f16(vb, mb, pR[jt], 0, 0, 0);
    }
  }
  // ---- m_relax band + einsum + tanh from fp32 M (128 threads) ----
  if (tid < 128) {
    int dir = tid >> 6, j = tid & 63;
    const float* Mrow = dir ? M32B : M32A;
    const float* Mcol = dir ? M32A : M32B;
    float acc = 0.f;
    for (int k = 0; k < 64; ++k) {
      float rx = 0.f;
#pragma unroll
      for (int i = -2; i <= 2; ++i) {
        int jj = j + i;
        if ((unsigned)jj < 64u) rx += Mrow[jj * 68 + k];
      }
      acc += rx * Mcol[k * 68 + j];
    }
    (dir ? mapR : mapL)[j] = tanhf(5.f * acc);
  }
  __syncthreads();  // B4: maps ready

  // ---- blend + store ----
#pragma unroll
  for (int jt = 0; jt < 4; ++jt) {
#pragma unroll
    for (int reg = 0; reg < 4; ++reg) {
      int c = 16 * w + 4 * lg + reg;
      int j = 16 * jt + l15;
      int hp2 = hb * 8 + (j >> 3), wp2 = wb * 8 + (j & 7);
      size_t off = ((size_t)(b * 64 + c)) * HW + hp2 * 512 + wp2;
      float ml = mapL[j], mr = mapR[j];
      outL[off] = xL[off] * (1.f - ml) + pL[jt][reg] * ml;
      outR[off] = xR[off] * (1.f - mr) + pR[jt][reg] * mr;
    }
  }
}

extern "C" void kernel_launch(void* const* d_in, const int* in_sizes, int n_in,
                              void* d_out, int out_size, void* d_ws, size_t ws_size,
                              hipStream_t stream) {
  const float* x_left = (const float*)d_in[0];
  const float* x_right = (const float*)d_in[1];
  const float* d_left = (const float*)d_in[2];
  const float* d_right = (const float*)d_in[3];
  const float* bn_gamma = (const float*)d_in[4];
  const float* bn_beta = (const float*)d_in[5];
  const float* rb_w1 = (const float*)d_in[6];
  const float* rb_b1 = (const float*)d_in[7];
  const float* rb_w2 = (const float*)d_in[8];
  const float* rb_b2 = (const float*)d_in[9];
  const float* qkv_w = (const float*)d_in[10];
  const float* qkv_b = (const float*)d_in[11];

  float* ws = (float*)d_ws;
  const size_t S = S_ELEMS;
  float* buf_t = ws;                 // S floats
  float* buf_r = ws + S;             // S floats
  float* knL = ws + 2 * S;           // S floats NHWC [b*HW+p][64]
  float* knR = ws + 3 * S;           // S floats
  unsigned short* vnL = (unsigned short*)(ws + 4 * S);   // S ushorts NHWC
  unsigned short* vnR = vnL + S;                         // S ushorts
  float2* partial = (float2*)(vnR + S);                  // 2048 float2
  float* stats = (float*)(partial + 2048);               // 256 floats

  float* out_left = (float*)d_out;   // stages Q_left (fp32 planes)
  float* out_right = out_left + S;   // stages Q_right

  bn_part_k<<<2048, 256, 0, stream>>>(x_left, x_right, partial);
  bn_fin_k<<<1, 128, 0, stream>>>(partial, bn_gamma, bn_beta, stats);

  for (int side = 0; side < 2; ++side) {
    const float* x = side ? x_right : x_left;
    float* qf = side ? out_right : out_left;
    float* kn = side ? knR : knL;
    unsigned short* vn = side ? vnR : vnL;
    const float* ss = stats + side * 128;
    conv3x3_t<true, true, false><<<4096, 256, 0, stream>>>(x, rb_w1, rb_b1, ss, nullptr, buf_t);
    conv3x3_t<false, false, true><<<4096, 256, 0, stream>>>(buf_t, rb_w2, rb_b2, ss, x, buf_r);
    qkv_k<<<4096, 256, 0, stream>>>(buf_r, qkv_w, qkv_b, qf, kn, vn);
  }
  attn_k<<<4096, 256, 0, stream>>>(out_left, out_right, knL, knR, vnL, vnR,
                                   d_left, d_right, x_left, x_right,
                                   out_left, out_right);
}

// Round 10
// 1087.587 us; speedup vs baseline: 1.4167x; 1.0783x over previous
//
#include <hip/hip_runtime.h>
#include <cstdint>

#define HW 131072        // H*W
#define S_ELEMS 16777216 // B*C*H*W

typedef __attribute__((ext_vector_type(8))) _Float16 f16x8;
typedef __attribute__((ext_vector_type(4))) float f32x4;

__device__ __forceinline__ float h2f(unsigned short u) {
  return (float)__builtin_bit_cast(_Float16, u);
}
__device__ __forceinline__ unsigned short f2h(float f) {
  return __builtin_bit_cast(unsigned short, (_Float16)f);
}

// ---------------- BN stats stage 1: partial sums (2 sides x 64 c x 16 slabs) ----------------
__global__ __launch_bounds__(256) void bn_part_k(const float* __restrict__ xL,
                                                 const float* __restrict__ xR,
                                                 float2* __restrict__ partial) {
  int bid = blockIdx.x;
  int side = bid >> 10, rest = bid & 1023;
  int c = rest >> 4, sl = rest & 15;
  const float* x = side ? xR : xL;
  const float4* p = (const float4*)(x + ((size_t)((sl >> 3) * 64 + c)) * HW + (size_t)(sl & 7) * 16384);
  float s1 = 0.f, s2 = 0.f;
  for (int i = threadIdx.x; i < 4096; i += 256) {
    float4 v = p[i];
    s1 += v.x + v.y + v.z + v.w;
    s2 += v.x * v.x + v.y * v.y + v.z * v.z + v.w * v.w;
  }
  for (int m = 32; m; m >>= 1) {
    s1 += __shfl_xor(s1, m, 64);
    s2 += __shfl_xor(s2, m, 64);
  }
  __shared__ float r1[4], r2[4];
  int wv = threadIdx.x >> 6;
  if ((threadIdx.x & 63) == 0) { r1[wv] = s1; r2[wv] = s2; }
  __syncthreads();
  if (threadIdx.x == 0) {
    partial[bid] = make_float2(r1[0] + r1[1] + r1[2] + r1[3], r2[0] + r2[1] + r2[2] + r2[3]);
  }
}

// ---------------- BN stats stage 2: finalize scale/shift ----------------
__global__ __launch_bounds__(128) void bn_fin_k(const float2* __restrict__ partial,
                                                const float* __restrict__ gamma,
                                                const float* __restrict__ beta,
                                                float* __restrict__ stats) {
  int tid = threadIdx.x;  // 0..127: side*64 + c
  int side = tid >> 6, c = tid & 63;
  float s1 = 0.f, s2 = 0.f;
  const float2* p = partial + (side * 1024 + c * 16);
  for (int s = 0; s < 16; ++s) { float2 v = p[s]; s1 += v.x; s2 += v.y; }
  float mu = s1 / 262144.f;
  float var = s2 / 262144.f - mu * mu;
  float rs = rsqrtf(var + 1e-5f);
  float sc = rs * gamma[c];
  stats[side * 128 + c] = sc;
  stats[side * 128 + 64 + c] = beta[c] - mu * sc;
}

// ---------------- tiled grouped 3x3 conv (8x32 tile) ----------------
template <bool BNIN, bool LEAKY, bool RES>
__global__ __launch_bounds__(256, 4) void conv3x3_t(const float* __restrict__ in,
                                                    const float* __restrict__ wgt,
                                                    const float* __restrict__ bias,
                                                    const float* __restrict__ ss,
                                                    const float* __restrict__ xres,
                                                    float* __restrict__ out) {
  __shared__ __align__(16) float sIn[16 * 10 * 36];
  __shared__ __align__(16) float sW[16 * 16 * 3 * 4];  // [o][ci][kh] float4 {w0,w1,w2,pad}
  __shared__ float sSc[16], sSh[16];
  int bid = blockIdx.x;
  int tw = bid & 15, th = (bid >> 4) & 31, g = (bid >> 9) & 3, b = bid >> 11;
  int tid = threadIdx.x;
  for (int e = tid; e < 2304; e += 256) {
    int o = e / 144, rem = e - o * 144, ci = rem / 9, k = rem - ci * 9;
    sW[((o * 16 + ci) * 3 + k / 3) * 4 + k % 3] = wgt[(g * 16 + o) * 144 + rem];
  }
  if ((BNIN || RES) && tid < 16) { sSc[tid] = ss[g * 16 + tid]; sSh[tid] = ss[64 + g * 16 + tid]; }
  // RACE FIX: sSc/sSh written by tid<16, read by all in staging loop.
  __syncthreads();
  int h0 = th * 8 - 1, w0 = tw * 32 - 1;
  const float* inb = in + ((size_t)(b * 64 + g * 16)) * HW;
  for (int e = tid; e < 5440; e += 256) {
    int ci = e / 340, rem = e - ci * 340, r = rem / 34, c = rem - r * 34;
    int h = h0 + r, w = w0 + c;
    float v = 0.f;
    if ((unsigned)h < 256u && (unsigned)w < 512u) {
      v = inb[(size_t)ci * HW + h * 512 + w];
      if (BNIN) v = v * sSc[ci] + sSh[ci];
    }
    sIn[ci * 360 + r * 36 + c] = v;
  }
  __syncthreads();
  int oh = tid >> 6;  // 0..3 output-channel quad
  int pxi = tid & 63;
  int row = pxi >> 3, col = (pxi & 7) * 4;
  float acc[4][4];
#pragma unroll
  for (int o = 0; o < 4; ++o) {
    float bz = bias[g * 16 + oh * 4 + o];
#pragma unroll
    for (int p = 0; p < 4; ++p) acc[o][p] = bz;
  }
  for (int ci = 0; ci < 16; ++ci) {
    float v[3][6];
    const float* base = sIn + ci * 360 + row * 36 + col;
#pragma unroll
    for (int kh = 0; kh < 3; ++kh) {
      float4 a4 = *(const float4*)(base + kh * 36);
      float2 a2 = *(const float2*)(base + kh * 36 + 4);
      v[kh][0] = a4.x; v[kh][1] = a4.y; v[kh][2] = a4.z; v[kh][3] = a4.w;
      v[kh][4] = a2.x; v[kh][5] = a2.y;
    }
    const float4* wb = (const float4*)sW + ((oh * 4) * 16 + ci) * 3;
#pragma unroll
    for (int o = 0; o < 4; ++o) {
      const float4* wo = wb + o * 48;
#pragma unroll
      for (int kh = 0; kh < 3; ++kh) {
        float4 wv = wo[kh];
#pragma unroll
        for (int p = 0; p < 4; ++p)
          acc[o][p] += wv.x * v[kh][p] + wv.y * v[kh][p + 1] + wv.z * v[kh][p + 2];
      }
    }
  }
  int h = th * 8 + row, wcol = tw * 32 + col;
#pragma unroll
  for (int o = 0; o < 4; ++o) {
    int cg = g * 16 + oh * 4 + o;
    size_t off = ((size_t)(b * 64 + cg)) * HW + h * 512 + wcol;
    float4 r4;
    float* rp = (float*)&r4;
    if (RES) {
      float4 x4 = *(const float4*)(xres + off);
      float sc = sSc[oh * 4 + o], sh = sSh[oh * 4 + o];
#pragma unroll
      for (int p = 0; p < 4; ++p) {
        float a = acc[o][p];
        if (LEAKY) a = a > 0.f ? a : 0.1f * a;
        rp[p] = a + ((float*)&x4)[p] * sc + sh;
      }
    } else {
#pragma unroll
      for (int p = 0; p < 4; ++p) {
        float a = acc[o][p];
        if (LEAKY) a = a > 0.f ? a : 0.1f * a;
        rp[p] = a;
      }
    }
    *(float4*)(out + off) = r4;
  }
}

// ---------------- 1x1 qkv conv: Q NHWC fp32; K NHWC fp32; V NHWC fp16 ----------------
__global__ __launch_bounds__(256) void qkv_k(const float* __restrict__ r,
                                             const float* __restrict__ wgt,
                                             const float* __restrict__ bias,
                                             float* __restrict__ qn,
                                             float* __restrict__ kn,
                                             unsigned short* __restrict__ vn) {
  __shared__ __align__(16) float sW[768];
  __shared__ float sB[48];
  int tid = threadIdx.x;
  int g = blockIdx.x >> 10;
  int idx = (blockIdx.x & 1023) * 256 + tid;  // over B*HW
  for (int e = tid; e < 768; e += 256) {
    int oo = e >> 4, ci = e & 15;
    sW[e] = wgt[(g * 48 + oo) * 16 + ci];
  }
  if (tid < 48) sB[tid] = bias[g * 48 + tid];
  __syncthreads();
  int p = idx & (HW - 1);
  int b = idx >> 17;
  const float* rb = r + ((size_t)(b * 64 + g * 16)) * HW + p;
  float in[16];
#pragma unroll
  for (int ci = 0; ci < 16; ++ci) in[ci] = rb[(size_t)ci * HW];
  size_t pxbase = ((size_t)b * HW + p) * 64;
  for (int oo = 0; oo < 48; oo += 4) {
    float a[4];
#pragma unroll
    for (int j = 0; j < 4; ++j) {
      float acc = sB[oo + j];
      const float4* w4 = (const float4*)(sW + (oo + j) * 16);
#pragma unroll
      for (int q = 0; q < 4; ++q) {
        float4 u = w4[q];
        acc += u.x * in[q * 4] + u.y * in[q * 4 + 1] + u.z * in[q * 4 + 2] + u.w * in[q * 4 + 3];
      }
      a[j] = acc;
    }
    int o = g * 48 + oo;
    if (o < 64) {
      *(float4*)(qn + pxbase + o) = *(float4*)a;
    } else if (o < 128) {
      *(float4*)(kn + pxbase + (o - 64)) = *(float4*)a;
    } else {
      uint2 pk;
      pk.x = (uint32_t)f2h(a[0]) | ((uint32_t)f2h(a[1]) << 16);
      pk.y = (uint32_t)f2h(a[2]) | ((uint32_t)f2h(a[3]) << 16);
      *(uint2*)(vn + pxbase + (o - 128)) = pk;
    }
  }
}

// ---------------- fused per-window attention: split-fp16 MFMA, all-NHWC, XCD swizzle ----
__global__ __launch_bounds__(256, 4) void attn_k(
    const float* __restrict__ qLn, const float* __restrict__ qRn,  // NHWC fp32
    const float* __restrict__ kLn, const float* __restrict__ kRn,  // NHWC fp32
    const unsigned short* __restrict__ vLn, const unsigned short* __restrict__ vRn, // NHWC fp16
    const float* __restrict__ dL, const float* __restrict__ dR,
    const float* __restrict__ xL, const float* __restrict__ xR,
    float* outL, float* outR) {
  // XCD-aware swizzle: consecutive windows -> same XCD L2 (4096 % 8 == 0, bijective)
  const int orig = blockIdx.x;
  const int n = (orig & 7) * 512 + (orig >> 3);
  const int b = n >> 11, hb = (n >> 6) & 31, wb = n & 63;
  const int tid = threadIdx.x;
  const int lane = tid & 63, w = tid >> 6;
  const int l15 = lane & 15, lg = lane >> 4;

  // K hi/lo (stride 72, fp16) — region reused after QK^T as fp32 M (stride 68)
  __shared__ __align__(16) unsigned short sK[4 * 64 * 72];   // 36864 B
  __shared__ float meanA[8], meanB[8], qsA[64], qsB[64], mapL[64], mapR[64];
  unsigned short* KHA = sK;
  unsigned short* KLA = sK + 64 * 72;
  unsigned short* KHB = sK + 2 * 64 * 72;
  unsigned short* KLB = sK + 3 * 64 * 72;
  float* M32A = (float*)sK;           // [64][68]
  float* M32B = (float*)sK + 64 * 68; // [64][68]

  const float* dLb = dL + (size_t)b * HW;
  const float* dRb = dR + (size_t)b * HW;
  const size_t nb = (size_t)b * HW;

  // ---- K gather (NHWC): 2 iters, 8 channels per thread per dir ----
  const int cc0 = (wb & 7) * 8;
#pragma unroll
  for (int it = 0; it < 2; ++it) {
    int slot = tid + 256 * it;           // 0..511
    int c2 = slot & 63, k8 = slot >> 6;  // k8 0..7
    int hh = 4 * c2 + (hb >> 3);
    int ww = (hb & 7) * 64 + k8 * 8 + (wb >> 3);
    int dpos = hh * 512 + ww;
    int iwr = ww - (int)dLb[dpos]; iwr = min(max(iwr, 0), 511);
    int iwl = ww + (int)dRb[dpos]; iwl = min(max(iwl, 0), 511);
    const float* pr = kRn + (nb + hh * 512 + iwr) * 64 + cc0;
    const float* pl = kLn + (nb + hh * 512 + iwl) * 64 + cc0;
    float fr[8], fl[8];
    *(float4*)&fr[0] = *(const float4*)pr;
    *(float4*)&fr[4] = *(const float4*)(pr + 4);
    *(float4*)&fl[0] = *(const float4*)pl;
    *(float4*)&fl[4] = *(const float4*)(pl + 4);
#pragma unroll
    for (int kl = 0; kl < 8; ++kl) {
      int k = 8 * k8 + kl;
      unsigned short hr = f2h(fr[kl]), hl = f2h(fl[kl]);
      KHA[k * 72 + c2] = hr; KLA[k * 72 + c2] = f2h(fr[kl] - h2f(hr));
      KHB[k * 72 + c2] = hl; KLB[k * 72 + c2] = f2h(fl[kl] - h2f(hl));
    }
  }

  // ---- Q load (NHWC fp32) + hi/lo split ----
  const int jr = 16 * w + l15;
  const int hp = hb * 8 + (jr >> 3), wp = wb * 8 + (jr & 7);
  const int gpix = hp * 512 + wp;
  const float* qlp = qLn + (nb + gpix) * 64;
  const float* qrp = qRn + (nb + gpix) * 64;
  float qv0[8], qv1[8], qw0[8], qw1[8];
  *(float4*)&qv0[0] = *(const float4*)(qlp + 8 * lg);
  *(float4*)&qv0[4] = *(const float4*)(qlp + 8 * lg + 4);
  *(float4*)&qv1[0] = *(const float4*)(qlp + 32 + 8 * lg);
  *(float4*)&qv1[4] = *(const float4*)(qlp + 32 + 8 * lg + 4);
  *(float4*)&qw0[0] = *(const float4*)(qrp + 8 * lg);
  *(float4*)&qw0[4] = *(const float4*)(qrp + 8 * lg + 4);
  *(float4*)&qw1[0] = *(const float4*)(qrp + 32 + 8 * lg);
  *(float4*)&qw1[4] = *(const float4*)(qrp + 32 + 8 * lg + 4);
  f16x8 qah0, qal0, qah1, qal1, qbh0, qbl0, qbh1, qbl1;
#pragma unroll
  for (int e = 0; e < 8; ++e) {
    _Float16 h;
    h = (_Float16)qv0[e]; qah0[e] = h; qal0[e] = (_Float16)(qv0[e] - (float)h);
    h = (_Float16)qv1[e]; qah1[e] = h; qal1[e] = (_Float16)(qv1[e] - (float)h);
    h = (_Float16)qw0[e]; qbh0[e] = h; qbl0[e] = (_Float16)(qw0[e] - (float)h);
    h = (_Float16)qw1[e]; qbh1[e] = h; qbl1[e] = (_Float16)(qw1[e] - (float)h);
  }

  // ---- V fragments (NHWC fp16: one b128 per (h,dir)) ----
  int4 vAr[2], vBr[2];
  {
    const int cv = 16 * w + l15;
#pragma unroll
    for (int h = 0; h < 2; ++h) {
      int hi = 4 * h + lg;
      int hh = 4 * cv + (hb >> 3);
      int ww = (hb & 7) * 64 + hi * 8 + (wb >> 3);
      int dpos = hh * 512 + ww;
      int iwr = ww - (int)dLb[dpos]; iwr = min(max(iwr, 0), 511);
      int iwl = ww + (int)dRb[dpos]; iwl = min(max(iwl, 0), 511);
      vAr[h] = *(const int4*)(vRn + (nb + hh * 512 + iwr) * 64 + cc0);
      vBr[h] = *(const int4*)(vLn + (nb + hh * 512 + iwl) * 64 + cc0);
    }
  }
  __syncthreads();  // B1: K staged

  // ---- K means per (dir,hi) over (wi,c): exact = hi+lo ----
  {
    int grp = tid >> 4, i = tid & 15;
    int dir = grp >> 3, hi = grp & 7;
    int off0 = (8 * hi + (i >> 1)) * 72 + (i & 1) * 32;
    const unsigned short* srcH = (dir ? KHB : KHA) + off0;
    const unsigned short* srcL = (dir ? KLB : KLA) + off0;
    float s = 0.f;
#pragma unroll
    for (int q = 0; q < 32; ++q) s += h2f(srcH[q]) + h2f(srcL[q]);
    for (int m = 8; m; m >>= 1) s += __shfl_xor(s, m, 64);
    if (i == 0) (dir ? meanB : meanA)[hi] = s * (1.f / 512.f);
  }
  // ---- qsum[j] (fp32 exact) ----
  {
    float sa = 0.f, sb = 0.f;
#pragma unroll
    for (int e = 0; e < 8; ++e) {
      sa += qv0[e] + qv1[e];
      sb += qw0[e] + qw1[e];
    }
    sa += __shfl_xor(sa, 16, 64); sa += __shfl_xor(sa, 32, 64);
    sb += __shfl_xor(sb, 16, 64); sb += __shfl_xor(sb, 32, 64);
    if (lane < 16) { qsA[jr] = sa; qsB[jr] = sb; }
  }
  __syncthreads();  // B2: means + qsums ready

  // ---- QK^T via split-fp16 MFMA: q.k ~= qh.kh + qh.kl + ql.kh ----
  f32x4 sA[4], sB[4];
#pragma unroll
  for (int t = 0; t < 4; ++t) { sA[t] = (f32x4){0.f, 0.f, 0.f, 0.f}; sB[t] = sA[t]; }
#pragma unroll
  for (int t = 0; t < 4; ++t) {
    int ro = (16 * t + l15) * 72 + 8 * lg;
    f16x8 kh0 = *(const f16x8*)(KHA + ro);
    f16x8 kl0 = *(const f16x8*)(KLA + ro);
    f16x8 kh1 = *(const f16x8*)(KHA + ro + 32);
    f16x8 kl1 = *(const f16x8*)(KLA + ro + 32);
    sA[t] = __builtin_amdgcn_mfma_f32_16x16x32_f16(qah0, kh0, sA[t], 0, 0, 0);
    sA[t] = __builtin_amdgcn_mfma_f32_16x16x32_f16(qah0, kl0, sA[t], 0, 0, 0);
    sA[t] = __builtin_amdgcn_mfma_f32_16x16x32_f16(qal0, kh0, sA[t], 0, 0, 0);
    sA[t] = __builtin_amdgcn_mfma_f32_16x16x32_f16(qah1, kh1, sA[t], 0, 0, 0);
    sA[t] = __builtin_amdgcn_mfma_f32_16x16x32_f16(qah1, kl1, sA[t], 0, 0, 0);
    sA[t] = __builtin_amdgcn_mfma_f32_16x16x32_f16(qal1, kh1, sA[t], 0, 0, 0);
    f16x8 mh0 = *(const f16x8*)(KHB + ro);
    f16x8 ml0 = *(const f16x8*)(KLB + ro);
    f16x8 mh1 = *(const f16x8*)(KHB + ro + 32);
    f16x8 ml1 = *(const f16x8*)(KLB + ro + 32);
    sB[t] = __builtin_amdgcn_mfma_f32_16x16x32_f16(qbh0, mh0, sB[t], 0, 0, 0);
    sB[t] = __builtin_amdgcn_mfma_f32_16x16x32_f16(qbh0, ml0, sB[t], 0, 0, 0);
    sB[t] = __builtin_amdgcn_mfma_f32_16x16x32_f16(qbl0, mh0, sB[t], 0, 0, 0);
    sB[t] = __builtin_amdgcn_mfma_f32_16x16x32_f16(qbh1, mh1, sB[t], 0, 0, 0);
    sB[t] = __builtin_amdgcn_mfma_f32_16x16x32_f16(qbh1, ml1, sB[t], 0, 0, 0);
    sB[t] = __builtin_amdgcn_mfma_f32_16x16x32_f16(qbl1, mh1, sB[t], 0, 0, 0);
  }
  // ---- mean-fold correction + in-register softmax over k ----
  {
    float qra[4], qrb2[4];
#pragma unroll
    for (int reg = 0; reg < 4; ++reg) {
      qra[reg] = qsA[16 * w + 4 * lg + reg];
      qrb2[reg] = qsB[16 * w + 4 * lg + reg];
    }
#pragma unroll
    for (int t = 0; t < 4; ++t) {
      float mA_ = meanA[2 * t + (l15 >> 3)];
      float mB_ = meanB[2 * t + (l15 >> 3)];
#pragma unroll
      for (int reg = 0; reg < 4; ++reg) {
        sA[t][reg] -= qra[reg] * mA_;
        sB[t][reg] -= qrb2[reg] * mB_;
      }
    }
#pragma unroll
    for (int reg = 0; reg < 4; ++reg) {
      float ma = sA[0][reg], mb = sB[0][reg];
#pragma unroll
      for (int t = 1; t < 4; ++t) { ma = fmaxf(ma, sA[t][reg]); mb = fmaxf(mb, sB[t][reg]); }
#pragma unroll
      for (int m = 1; m <= 8; m <<= 1) {
        ma = fmaxf(ma, __shfl_xor(ma, m, 64));
        mb = fmaxf(mb, __shfl_xor(mb, m, 64));
      }
      float sa = 0.f, sb = 0.f;
#pragma unroll
      for (int t = 0; t < 4; ++t) {
        float ea = __expf(sA[t][reg] - ma), eb = __expf(sB[t][reg] - mb);
        sA[t][reg] = ea; sB[t][reg] = eb;
        sa += ea; sb += eb;
      }
#pragma unroll
      for (int m = 1; m <= 8; m <<= 1) {
        sa += __shfl_xor(sa, m, 64);
        sb += __shfl_xor(sb, m, 64);
      }
      float ra = 1.f / sa, rb = 1.f / sb;
#pragma unroll
      for (int t = 0; t < 4; ++t) { sA[t][reg] *= ra; sB[t][reg] *= rb; }
    }
  }
  __syncthreads();  // B2.5: all K reads done; overlay M32 onto K region

  // ---- write M fp32 (stride 68; serves both PV and m-map path) ----
#pragma unroll
  for (int t = 0; t < 4; ++t)
#pragma unroll
    for (int reg = 0; reg < 4; ++reg) {
      int jrow = 16 * w + 4 * lg + reg, kcol = 16 * t + l15;
      M32A[jrow * 68 + kcol] = sA[t][reg];
      M32B[jrow * 68 + kcol] = sB[t][reg];
    }
  __syncthreads();  // B3: M complete

  // ---- PV via MFMA (fp16 cvt from fp32 M): X^T[c][j] = sum_k V_sel[k][c] * M[j][k] ----
  f32x4 pL[4], pR[4];
#pragma unroll
  for (int t = 0; t < 4; ++t) { pL[t] = (f32x4){0.f, 0.f, 0.f, 0.f}; pR[t] = pL[t]; }
#pragma unroll
  for (int h = 0; h < 2; ++h) {
    f16x8 va = __builtin_bit_cast(f16x8, vAr[h]);
    f16x8 vb = __builtin_bit_cast(f16x8, vBr[h]);
#pragma unroll
    for (int jt = 0; jt < 4; ++jt) {
      const float* mra = M32A + (16 * jt + l15) * 68 + 32 * h + 8 * lg;
      const float* mrb = M32B + (16 * jt + l15) * 68 + 32 * h + 8 * lg;
      float fa[8], fb[8];
      *(float4*)&fa[0] = *(const float4*)mra;
      *(float4*)&fa[4] = *(const float4*)(mra + 4);
      *(float4*)&fb[0] = *(const float4*)mrb;
      *(float4*)&fb[4] = *(const float4*)(mrb + 4);
      f16x8 ma, mb;
#pragma unroll
      for (int e = 0; e < 8; ++e) { ma[e] = (_Float16)fa[e]; mb[e] = (_Float16)fb[e]; }
      pL[jt] = __builtin_amdgcn_mfma_f32_16x16x32_f16(va, ma, pL[jt], 0, 0, 0);
      pR[jt] = __builtin_amdgcn_mfma_f32_16x16x32_f16(vb, mb, pR[jt], 0, 0, 0);
    }
  }
  // ---- m_relax band + einsum + tanh from fp32 M (128 threads) ----
  if (tid < 128) {
    int dir = tid >> 6, j = tid & 63;
    const float* Mrow = dir ? M32B : M32A;
    const float* Mcol = dir ? M32A : M32B;
    float acc = 0.f;
    for (int k = 0; k < 64; ++k) {
      float rx = 0.f;
#pragma unroll
      for (int i = -2; i <= 2; ++i) {
        int jj = j + i;
        if ((unsigned)jj < 64u) rx += Mrow[jj * 68 + k];
      }
      acc += rx * Mcol[k * 68 + j];
    }
    (dir ? mapR : mapL)[j] = tanhf(5.f * acc);
  }
  __syncthreads();  // B4: maps ready

  // ---- blend + store ----
#pragma unroll
  for (int jt = 0; jt < 4; ++jt) {
#pragma unroll
    for (int reg = 0; reg < 4; ++reg) {
      int c = 16 * w + 4 * lg + reg;
      int j = 16 * jt + l15;
      int hp2 = hb * 8 + (j >> 3), wp2 = wb * 8 + (j & 7);
      size_t off = ((size_t)(b * 64 + c)) * HW + hp2 * 512 + wp2;
      float ml = mapL[j], mr = mapR[j];
      outL[off] = xL[off] * (1.f - ml) + pL[jt][reg] * ml;
      outR[off] = xR[off] * (1.f - mr) + pR[jt][reg] * mr;
    }
  }
}

extern "C" void kernel_launch(void* const* d_in, const int* in_sizes, int n_in,
                              void* d_out, int out_size, void* d_ws, size_t ws_size,
                              hipStream_t stream) {
  const float* x_left = (const float*)d_in[0];
  const float* x_right = (const float*)d_in[1];
  const float* d_left = (const float*)d_in[2];
  const float* d_right = (const float*)d_in[3];
  const float* bn_gamma = (const float*)d_in[4];
  const float* bn_beta = (const float*)d_in[5];
  const float* rb_w1 = (const float*)d_in[6];
  const float* rb_b1 = (const float*)d_in[7];
  const float* rb_w2 = (const float*)d_in[8];
  const float* rb_b2 = (const float*)d_in[9];
  const float* qkv_w = (const float*)d_in[10];
  const float* qkv_b = (const float*)d_in[11];

  float* ws = (float*)d_ws;
  const size_t S = S_ELEMS;
  float* buf_t = ws;                 // S floats
  float* buf_r = ws + S;             // S floats
  float* knL = ws + 2 * S;           // S floats NHWC [b*HW+p][64]
  float* knR = ws + 3 * S;           // S floats
  unsigned short* vnL = (unsigned short*)(ws + 4 * S);   // S ushorts NHWC
  unsigned short* vnR = vnL + S;                         // S ushorts (ends at ws+5S)
  float* qnL = ws + 5 * S;           // S floats NHWC
  float* qnR = ws + 6 * S;           // S floats (total: exactly 7S, round-1-proven)

  // partial/stats live at the head of d_out: written by bn kernels, read by convs,
  // overwritten by attn's blend at the very end (stream order guarantees safety).
  float* out_left = (float*)d_out;
  float* out_right = out_left + S;
  float2* partial = (float2*)d_out;              // 2048 float2 = 4096 floats
  float* stats = (float*)d_out + 4096;           // 256 floats

  bn_part_k<<<2048, 256, 0, stream>>>(x_left, x_right, partial);
  bn_fin_k<<<1, 128, 0, stream>>>(partial, bn_gamma, bn_beta, stats);

  for (int side = 0; side < 2; ++side) {
    const float* x = side ? x_right : x_left;
    float* qn = side ? qnR : qnL;
    float* kn = side ? knR : knL;
    unsigned short* vn = side ? vnR : vnL;
    const float* ss = stats + side * 128;
    conv3x3_t<true, true, false><<<4096, 256, 0, stream>>>(x, rb_w1, rb_b1, ss, nullptr, buf_t);
    conv3x3_t<false, false, true><<<4096, 256, 0, stream>>>(buf_t, rb_w2, rb_b2, ss, x, buf_r);
    qkv_k<<<4096, 256, 0, stream>>>(buf_r, qkv_w, qkv_b, qn, kn, vn);
  }
  attn_k<<<4096, 256, 0, stream>>>(qnL, qnR, knL, knR, vnL, vnR,
                                   d_left, d_right, x_left, x_right,
                                   out_left, out_right);
}